// Round 11
// baseline (265.311 us; speedup 1.0000x reference)
//
#include <hip/hip_runtime.h>
#include <hip/hip_bf16.h>

#define B_   8
#define N_   8192
#define S_   2048
#define D1_  128
#define D2_  256
#define CIN_ 384
#define C1_  256
#define C2_  128
#define ROWS_ (B_ * N_)   // 65536

typedef __attribute__((ext_vector_type(8))) short short8v;
typedef __attribute__((ext_vector_type(4))) float f32x4;
typedef __attribute__((ext_vector_type(16))) float f32x16;

__device__ inline unsigned short f2bf(float x) {
    __hip_bfloat16 h = __float2bfloat16(x);
    unsigned short u;
    __builtin_memcpy(&u, &h, 2);
    return u;
}
__device__ inline float bf2f(unsigned short u) {
    unsigned int x = ((unsigned int)u) << 16;
    float f;
    __builtin_memcpy(&f, &x, 4);
    return f;
}
__device__ inline unsigned int f2u(float x) { unsigned int u; __builtin_memcpy(&u, &x, 4); return u; }
__device__ inline float u2f(unsigned int u) { float x; __builtin_memcpy(&x, &u, 4); return x; }

// ---------------------------------------------------------------------------
// Pack xyz2 -> {x,y,z,r2} float4 (passed rounds 9/10; r2 bit-identical)
// ---------------------------------------------------------------------------
__global__ __launch_bounds__(256) void pack_kernel(
    const float* __restrict__ xyz2, float4* __restrict__ pk)
{
#pragma clang fp contract(off)
    int i = blockIdx.x * 256 + threadIdx.x;
    float a = xyz2[i * 3 + 0], c = xyz2[i * 3 + 1], d = xyz2[i * 3 + 2];
    float4 v; v.x = a; v.y = c; v.z = d; v.w = (a * a + c * c) + d * d;
    pk[i] = v;
}

// ---------------------------------------------------------------------------
// 3-NN two-pass (logic byte-identical to passing rounds 7-10). SMEM delivery,
// now 4x s_load_dwordx16 per wait (16 candidates/group) to halve stall count.
// ---------------------------------------------------------------------------
__global__ __launch_bounds__(1024) void nn3_kernel(
    const float* __restrict__ xyz1, const float4* __restrict__ pk,
    int* __restrict__ nidx, float* __restrict__ nw)
{
#pragma clang fp contract(off)
    __shared__ unsigned int pa[8][128][3];
    __shared__ int   pb[8][128][2];
    __shared__ int   pc[8][128];
    __shared__ float fvv[128][3];
    const int tid = threadIdx.x;
    const int b = blockIdx.y;
    const int q = tid & 127;
    const int chunk = tid >> 7;                // wave-uniform (128-aligned)
    const int s0 = chunk * 256;
    const unsigned s0u = __builtin_amdgcn_readfirstlane((unsigned)s0);
    const char* cp = (const char*)(pk + (size_t)b * S_) + (size_t)s0u * 16u;

    const int n = blockIdx.x * 128 + q;
    const float* p = xyz1 + ((size_t)b * N_ + n) * 3;
    const float px = p[0], py = p[1], pz = p[2];
    const float r1 = (px * px + py * py) + pz * pz;

    // ---- pass A ----
    float e1 = 3.4e38f, e2 = 3.4e38f, e3 = 3.4e38f;
    for (int g = 0; g < 16; ++g) {
        f32x16 c0, c1, c2, c3;
        asm volatile("s_load_dwordx16 %0, %4, 0\n\t"
                     "s_load_dwordx16 %1, %4, 64\n\t"
                     "s_load_dwordx16 %2, %4, 128\n\t"
                     "s_load_dwordx16 %3, %4, 192\n\t"
                     "s_waitcnt lgkmcnt(0)"
                     : "=&s"(c0), "=&s"(c1), "=&s"(c2), "=&s"(c3)
                     : "s"(cp + (size_t)g * 256));
#pragma unroll
        for (int j = 0; j < 16; ++j) {
            float sx = (j < 4) ? c0[4*j+0] : (j < 8) ? c1[4*(j-4)+0] : (j < 12) ? c2[4*(j-8)+0] : c3[4*(j-12)+0];
            float sy = (j < 4) ? c0[4*j+1] : (j < 8) ? c1[4*(j-4)+1] : (j < 12) ? c2[4*(j-8)+1] : c3[4*(j-12)+1];
            float sz = (j < 4) ? c0[4*j+2] : (j < 8) ? c1[4*(j-4)+2] : (j < 12) ? c2[4*(j-8)+2] : c3[4*(j-12)+2];
            float sr = (j < 4) ? c0[4*j+3] : (j < 8) ? c1[4*(j-4)+3] : (j < 12) ? c2[4*(j-8)+3] : c3[4*(j-12)+3];
            float dot = (px * sx + py * sy) + pz * sz;
            float d = (r1 - 2.0f * dot) + sr;
            float n1 = fminf(e1, d);
            float n2 = __builtin_amdgcn_fmed3f(d, e1, e2);
            float n3 = __builtin_amdgcn_fmed3f(d, e2, e3);
            e1 = n1; e2 = n2; e3 = n3;
        }
    }
    pa[chunk][q][0] = f2u(e1); pa[chunk][q][1] = f2u(e2); pa[chunk][q][2] = f2u(e3);
    __syncthreads();

    float v1f = 0.f, v2f = 0.f, v3f = 0.f;
    if (tid < 128) {
        float m1 = u2f(pa[0][tid][0]), m2 = u2f(pa[0][tid][1]), m3 = u2f(pa[0][tid][2]);
#pragma unroll
        for (int c = 1; c < 8; ++c)
#pragma unroll
            for (int e = 0; e < 3; ++e) {
                float x = u2f(pa[c][tid][e]);
                float n1 = fminf(m1, x);
                float n2 = __builtin_amdgcn_fmed3f(x, m1, m2);
                float n3 = __builtin_amdgcn_fmed3f(x, m2, m3);
                m1 = n1; m2 = n2; m3 = n3;
            }
        v1f = m1; v2f = m2; v3f = m3;
        fvv[tid][0] = m1; fvv[tid][1] = m2; fvv[tid][2] = m3;
    }
    __syncthreads();
    const float t1 = fvv[q][0], t2 = fvv[q][1], t3 = fvv[q][2];

    // ---- pass B ----
    int a1 = 0x7FFFFFFF, a2 = 0x7FFFFFFF, a3 = 0x7FFFFFFF;
    int b1 = 0x7FFFFFFF, b2 = 0x7FFFFFFF;
    int c1m = 0x7FFFFFFF;
    for (int g = 0; g < 16; ++g) {
        f32x16 c0, c1, c2, c3;
        asm volatile("s_load_dwordx16 %0, %4, 0\n\t"
                     "s_load_dwordx16 %1, %4, 64\n\t"
                     "s_load_dwordx16 %2, %4, 128\n\t"
                     "s_load_dwordx16 %3, %4, 192\n\t"
                     "s_waitcnt lgkmcnt(0)"
                     : "=&s"(c0), "=&s"(c1), "=&s"(c2), "=&s"(c3)
                     : "s"(cp + (size_t)g * 256));
#pragma unroll
        for (int j = 0; j < 16; ++j) {
            float sx = (j < 4) ? c0[4*j+0] : (j < 8) ? c1[4*(j-4)+0] : (j < 12) ? c2[4*(j-8)+0] : c3[4*(j-12)+0];
            float sy = (j < 4) ? c0[4*j+1] : (j < 8) ? c1[4*(j-4)+1] : (j < 12) ? c2[4*(j-8)+1] : c3[4*(j-12)+1];
            float sz = (j < 4) ? c0[4*j+2] : (j < 8) ? c1[4*(j-4)+2] : (j < 12) ? c2[4*(j-8)+2] : c3[4*(j-12)+2];
            float sr = (j < 4) ? c0[4*j+3] : (j < 8) ? c1[4*(j-4)+3] : (j < 12) ? c2[4*(j-8)+3] : c3[4*(j-12)+3];
            float dot = (px * sx + py * sy) + pz * sz;
            float d = (r1 - 2.0f * dot) + sr;
            if (d <= t3) {
                const int s = s0 + g * 16 + j;
                int u1 = (d == t1) ? s : 0x7FFFFFFF;
                int u2 = (d == t2) ? s : 0x7FFFFFFF;
                int na3 = min(a3, max(a2, u1));
                int na2 = min(a2, max(a1, u1));
                a1 = min(a1, u1); a2 = na2; a3 = na3;
                int nb2 = min(b2, max(b1, u2));
                b1 = min(b1, u2); b2 = nb2;
                c1m = (d == t3) ? min(c1m, s) : c1m;
            }
        }
    }
    pa[chunk][q][0] = (unsigned)a1; pa[chunk][q][1] = (unsigned)a2; pa[chunk][q][2] = (unsigned)a3;
    pb[chunk][q][0] = b1; pb[chunk][q][1] = b2;
    pc[chunk][q] = c1m;
    __syncthreads();

    if (tid < 128) {
        int A1 = 0x7FFFFFFF, A2 = 0x7FFFFFFF, A3 = 0x7FFFFFFF;
        int B1 = 0x7FFFFFFF, B2 = 0x7FFFFFFF;
        int C1m = 0x7FFFFFFF;
#pragma unroll
        for (int c = 0; c < 8; ++c) {
#pragma unroll
            for (int e = 0; e < 3; ++e) {
                int x = (int)pa[c][tid][e];
                int nA3 = min(A3, max(A2, x));
                int nA2 = min(A2, max(A1, x));
                A1 = min(A1, x); A2 = nA2; A3 = nA3;
            }
#pragma unroll
            for (int e = 0; e < 2; ++e) {
                int x = pb[c][tid][e];
                int nB2 = min(B2, max(B1, x));
                B1 = min(B1, x); B2 = nB2;
            }
            C1m = min(C1m, pc[c][tid]);
        }
        int j1 = A1, j2, j3;
        if (v2f == v1f) j2 = A2; else j2 = B1;
        if (v3f == v2f) j3 = (v2f == v1f) ? A3 : B2;
        else            j3 = C1m;
        float ra = 1.0f / (v1f + 1e-8f);
        float rb = 1.0f / (v2f + 1e-8f);
        float rc = 1.0f / (v3f + 1e-8f);
        float sum = (ra + rb) + rc;
        size_t o = ((size_t)b * N_ + blockIdx.x * 128 + tid) * 3;
        nidx[o + 0] = j1; nidx[o + 1] = j2; nidx[o + 2] = j3;
        nw[o + 0] = ra / sum; nw[o + 1] = rb / sum; nw[o + 2] = rc / sum;
    }
}

// weights -> bf16
__global__ void cvtw_kernel(const float* __restrict__ w1, const float* __restrict__ w2,
                            unsigned short* __restrict__ w1b, unsigned short* __restrict__ w2b)
{
    int i = blockIdx.x * 256 + threadIdx.x;
    if (i < C1_ * CIN_) w1b[i] = f2bf(w1[i]);
    else {
        int j = i - C1_ * CIN_;
        if (j < C2_ * C1_) w2b[j] = f2bf(w2[j]);
    }
}

// p1, p2 -> bf16 (float4 -> ushort4)
__global__ __launch_bounds__(256) void prep_kernel(
    const float* __restrict__ p1, const float* __restrict__ p2,
    unsigned short* __restrict__ p1b, unsigned short* __restrict__ p2b)
{
    int i = blockIdx.x * 256 + threadIdx.x;
    const int NP1 = ROWS_ * D1_ / 4;          // 2,097,152
    if (i < NP1) {
        float4 v = ((const float4*)p1)[i];
        ushort4 r; r.x = f2bf(v.x); r.y = f2bf(v.y); r.z = f2bf(v.z); r.w = f2bf(v.w);
        ((ushort4*)p1b)[i] = r;
    } else {
        int k = i - NP1;                      // < 1,048,576
        float4 v = ((const float4*)p2)[k];
        ushort4 r; r.x = f2bf(v.x); r.y = f2bf(v.y); r.z = f2bf(v.z); r.w = f2bf(v.w);
        ((ushort4*)p2b)[k] = r;
    }
}

// ---------------------------------------------------------------------------
// Z-GEMM: Z[r][col] = sum_k p2b[r][k] * w1[col][128+k]   (r = b*2048+s)
// Pure global_load_lds staging (proven MODE0 structure), f32 out, no epilogue.
// ---------------------------------------------------------------------------
__global__ __launch_bounds__(256) void zgemm_kernel(
    const unsigned short* __restrict__ A,   // p2b [16384][256]
    const unsigned short* __restrict__ W,   // w1b [256][384]
    float* __restrict__ Z)                  // [16384][256] f32
{
    __shared__ unsigned short As[4][128][8];
    __shared__ unsigned short Bs[4][128][8];
    const int tid = threadIdx.x;
    const int wave = tid >> 6, lane = tid & 63;
    const int chunkw = (blockIdx.x & 7) * (gridDim.x >> 3) + (blockIdx.x >> 3);
    const int r0 = (chunkw >> 1) * 128;
    const int n0 = (chunkw & 1) * 128;
    const int wr = wave >> 1, wc = wave & 1;
    const int kh = lane >> 4, l16 = lane & 15;

    f32x4 acc[4][4];
#pragma unroll
    for (int m = 0; m < 4; ++m)
#pragma unroll
        for (int n = 0; n < 4; ++n)
            acc[m][n] = (f32x4){0.f, 0.f, 0.f, 0.f};

    const int slotbase = wave * 64;
    for (int k0 = 0; k0 < 256; k0 += 32) {
        __syncthreads();
#pragma unroll
        for (int p = 0; p < 2; ++p) {
            const int sb = p * 256 + slotbase;
            const int s = sb + lane;
            const int kg = s >> 7, i = s & 127;
            const unsigned short* gA = A + (size_t)(r0 + i) * 256 + k0 + kg * 8;
            const unsigned short* gB = W + (size_t)(n0 + i) * CIN_ + D1_ + k0 + kg * 8;
            __builtin_amdgcn_global_load_lds(
                (const __attribute__((address_space(1))) void*)gA,
                (__attribute__((address_space(3))) void*)(&As[0][0][0] + (size_t)sb * 8),
                16, 0, 0);
            __builtin_amdgcn_global_load_lds(
                (const __attribute__((address_space(1))) void*)gB,
                (__attribute__((address_space(3))) void*)(&Bs[0][0][0] + (size_t)sb * 8),
                16, 0, 0);
        }
        __syncthreads();

        short8v af[4], bf[4];
#pragma unroll
        for (int m = 0; m < 4; ++m)
            af[m] = *(const short8v*)&As[kh][wr * 64 + m * 16 + l16][0];
#pragma unroll
        for (int n = 0; n < 4; ++n)
            bf[n] = *(const short8v*)&Bs[kh][wc * 64 + n * 16 + l16][0];
#pragma unroll
        for (int m = 0; m < 4; ++m)
#pragma unroll
            for (int n = 0; n < 4; ++n)
                acc[m][n] = __builtin_amdgcn_mfma_f32_16x16x32_bf16(
                    af[m], bf[n], acc[m][n], 0, 0, 0);
    }

#pragma unroll
    for (int n = 0; n < 4; ++n) {
        const int col = n0 + wc * 64 + n * 16 + l16;
#pragma unroll
        for (int m = 0; m < 4; ++m) {
            const int rowb = r0 + wr * 64 + m * 16 + kh * 4;
#pragma unroll
            for (int j = 0; j < 4; ++j)
                Z[(size_t)(rowb + j) * 256 + col] = acc[m][n][j];
        }
    }
}

// ---------------------------------------------------------------------------
// GEMM1': y1 = p1b @ W1a^T + b1 + sum_k nw_k * Z[nidx_k]   (K=128, one-shot
// LDS stage, single barrier pair; Z-gather in epilogue, L2-resident slab).
// Fused BN-stats. Output bf16.
// ---------------------------------------------------------------------------
__global__ __launch_bounds__(256) void gemm_p1_kernel(
    const unsigned short* __restrict__ A,   // p1b [65536][128]
    const unsigned short* __restrict__ W,   // w1b [256][384] (cols 0..127)
    const float* __restrict__ bias,
    const int* __restrict__ nidx, const float* __restrict__ nw,
    const float* __restrict__ Zg,           // [16384][256] f32
    unsigned short* __restrict__ out,       // y1b [65536][256]
    float* __restrict__ sums, float* __restrict__ ssqs)
{
    __shared__ unsigned short As[16][128][8];   // 32 KiB
    __shared__ unsigned short Bs[16][128][8];   // 32 KiB
    __shared__ float csum[128], csq[128];
    __shared__ int   lidx[128][3];
    __shared__ float lw[128][3];
    const int tid = threadIdx.x;
    const int wave = tid >> 6, lane = tid & 63;
    const int chunkw = (blockIdx.x & 7) * (gridDim.x >> 3) + (blockIdx.x >> 3);
    const int r0 = (chunkw >> 1) * 128;
    const int n0 = (chunkw & 1) * 128;
    const int wr = wave >> 1, wc = wave & 1;
    const int kh = lane >> 4, l16 = lane & 15;

    // one-shot stage: 2048 slots each for A and B
    const int slotbase = wave * 64;
#pragma unroll
    for (int t = 0; t < 8; ++t) {
        const int sb = t * 256 + slotbase;
        const int s = sb + lane;
        const int kg = s >> 7, i = s & 127;
        const unsigned short* gA = A + (size_t)(r0 + i) * D1_ + kg * 8;
        const unsigned short* gB = W + (size_t)(n0 + i) * CIN_ + kg * 8;
        __builtin_amdgcn_global_load_lds(
            (const __attribute__((address_space(1))) void*)gA,
            (__attribute__((address_space(3))) void*)(&As[0][0][0] + (size_t)sb * 8),
            16, 0, 0);
        __builtin_amdgcn_global_load_lds(
            (const __attribute__((address_space(1))) void*)gB,
            (__attribute__((address_space(3))) void*)(&Bs[0][0][0] + (size_t)sb * 8),
            16, 0, 0);
    }
    if (tid < 128) {
        csum[tid] = 0.f; csq[tid] = 0.f;
        const int row = r0 + tid;
        lidx[tid][0] = nidx[row * 3 + 0];
        lidx[tid][1] = nidx[row * 3 + 1];
        lidx[tid][2] = nidx[row * 3 + 2];
        lw[tid][0] = nw[row * 3 + 0];
        lw[tid][1] = nw[row * 3 + 1];
        lw[tid][2] = nw[row * 3 + 2];
    }
    __syncthreads();

    f32x4 acc[4][4];
#pragma unroll
    for (int m = 0; m < 4; ++m)
#pragma unroll
        for (int n = 0; n < 4; ++n)
            acc[m][n] = (f32x4){0.f, 0.f, 0.f, 0.f};

#pragma unroll
    for (int st = 0; st < 4; ++st) {
        short8v af[4], bf[4];
#pragma unroll
        for (int m = 0; m < 4; ++m)
            af[m] = *(const short8v*)&As[st * 4 + kh][wr * 64 + m * 16 + l16][0];
#pragma unroll
        for (int n = 0; n < 4; ++n)
            bf[n] = *(const short8v*)&Bs[st * 4 + kh][wc * 64 + n * 16 + l16][0];
#pragma unroll
        for (int m = 0; m < 4; ++m)
#pragma unroll
            for (int n = 0; n < 4; ++n)
                acc[m][n] = __builtin_amdgcn_mfma_f32_16x16x32_bf16(
                    af[m], bf[n], acc[m][n], 0, 0, 0);
    }

    // epilogue: bias + Z-gather + stats + store
    const float* Zb = Zg + (size_t)(r0 >> 13) * S_ * 256;   // batch slab (2 MB, L2)
#pragma unroll
    for (int n = 0; n < 4; ++n) {
        const int cl = wc * 64 + n * 16 + l16;
        const int col = n0 + cl;
        const float bv = bias[col];
        float s = 0.f, qs = 0.f;
#pragma unroll
        for (int m = 0; m < 4; ++m) {
            const int rl0 = wr * 64 + m * 16 + kh * 4;
#pragma unroll
            for (int j = 0; j < 4; ++j) {
                const int rl = rl0 + j;
                const float z = lw[rl][0] * Zb[(size_t)lidx[rl][0] * 256 + col]
                              + lw[rl][1] * Zb[(size_t)lidx[rl][1] * 256 + col]
                              + lw[rl][2] * Zb[(size_t)lidx[rl][2] * 256 + col];
                const float v = (acc[m][n][j] + bv) + z;
                s += v; qs += v * v;
                out[(size_t)(r0 + rl) * C1_ + col] = f2bf(v);
            }
        }
        atomicAdd(&csum[cl], s);
        atomicAdd(&csq[cl], qs);
    }
    __syncthreads();
    if (tid < 128) {
        atomicAdd(&sums[n0 + tid], csum[tid]);
        atomicAdd(&ssqs[n0 + tid], csq[tid]);
    }
}

// ---------------------------------------------------------------------------
// GEMM2 (MODE1, unchanged from passing rounds): A = relu(y1b*scale+shift),
// reg-staged; fused bias + stats. Output f32.
// ---------------------------------------------------------------------------
__global__ __launch_bounds__(256) void gemm2_kernel(
    const unsigned short* __restrict__ Abf,  // y1b [65536][256]
    const unsigned short* __restrict__ W,    // w2b [128][256]
    const float* __restrict__ bias,
    const float* __restrict__ scale, const float* __restrict__ shift,
    float* __restrict__ outf,
    float* __restrict__ sums, float* __restrict__ ssqs)
{
    __shared__ unsigned short As[4][128][8];
    __shared__ unsigned short Bs[4][128][8];
    __shared__ float csum[128], csq[128];
    const int tid = threadIdx.x;
    const int wave = tid >> 6, lane = tid & 63;
    const int chunkw = (blockIdx.x & 7) * (gridDim.x >> 3) + (blockIdx.x >> 3);
    const int r0 = chunkw * 128;
    const int n0 = 0;
    const int wr = wave >> 1, wc = wave & 1;
    const int kh = lane >> 4, l16 = lane & 15;

    if (tid < 128) { csum[tid] = 0.f; csq[tid] = 0.f; }

    f32x4 acc[4][4];
#pragma unroll
    for (int m = 0; m < 4; ++m)
#pragma unroll
        for (int n = 0; n < 4; ++n)
            acc[m][n] = (f32x4){0.f, 0.f, 0.f, 0.f};

    const int slotbase = wave * 64;
    int rowA[2];
#pragma unroll
    for (int p = 0; p < 2; ++p)
        rowA[p] = r0 + ((p * 256 + slotbase + lane) & 127);

    for (int k0 = 0; k0 < C1_; k0 += 32) {
        __syncthreads();
#pragma unroll
        for (int p = 0; p < 2; ++p) {
            const int sb = p * 256 + slotbase;
            const int s = sb + lane;
            const int kg = s >> 7, i = s & 127;
            const unsigned short* gB = W + (size_t)(n0 + i) * C1_ + k0 + kg * 8;
            __builtin_amdgcn_global_load_lds(
                (const __attribute__((address_space(1))) void*)gB,
                (__attribute__((address_space(3))) void*)(&Bs[0][0][0] + (size_t)sb * 8),
                16, 0, 0);
            const int c0 = k0 + kg * 8;
            short8v v = *(const short8v*)(Abf + (size_t)rowA[p] * C1_ + c0);
            float4 sca = *(const float4*)(scale + c0);
            float4 scb = *(const float4*)(scale + c0 + 4);
            float4 sha = *(const float4*)(shift + c0);
            float4 shb = *(const float4*)(shift + c0 + 4);
            float sc[8] = {sca.x, sca.y, sca.z, sca.w, scb.x, scb.y, scb.z, scb.w};
            float sh[8] = {sha.x, sha.y, sha.z, sha.w, shb.x, shb.y, shb.z, shb.w};
            short8v r;
#pragma unroll
            for (int j = 0; j < 8; ++j) {
                float f = bf2f((unsigned short)v[j]);
                f = fmaxf(fmaf(f, sc[j], sh[j]), 0.0f);
                r[j] = (short)f2bf(f);
            }
            *(short8v*)&As[kg][s & 127][0] = r;
        }
        __syncthreads();

        short8v af[4], bf[4];
#pragma unroll
        for (int m = 0; m < 4; ++m)
            af[m] = *(const short8v*)&As[kh][wr * 64 + m * 16 + l16][0];
#pragma unroll
        for (int n = 0; n < 4; ++n)
            bf[n] = *(const short8v*)&Bs[kh][wc * 64 + n * 16 + l16][0];
#pragma unroll
        for (int m = 0; m < 4; ++m)
#pragma unroll
            for (int n = 0; n < 4; ++n)
                acc[m][n] = __builtin_amdgcn_mfma_f32_16x16x32_bf16(
                    af[m], bf[n], acc[m][n], 0, 0, 0);
    }

#pragma unroll
    for (int n = 0; n < 4; ++n) {
        const int cl = wc * 64 + n * 16 + l16;
        const int col = n0 + cl;
        const float bv = bias[col];
        float s = 0.f, qs = 0.f;
#pragma unroll
        for (int m = 0; m < 4; ++m) {
            const int rowb = r0 + wr * 64 + m * 16 + kh * 4;
#pragma unroll
            for (int j = 0; j < 4; ++j) {
                const float v = acc[m][n][j] + bv;
                s += v; qs += v * v;
                outf[(size_t)(rowb + j) * C2_ + col] = v;
            }
        }
        atomicAdd(&csum[cl], s);
        atomicAdd(&csq[cl], qs);
    }
    __syncthreads();
    if (tid < 128) {
        atomicAdd(&sums[n0 + tid], csum[tid]);
        atomicAdd(&ssqs[n0 + tid], csq[tid]);
    }
}

__global__ void finalize_kernel(const float* __restrict__ sums,
                                const float* __restrict__ ssqs,
                                const float* __restrict__ g,
                                const float* __restrict__ be,
                                float* __restrict__ scale,
                                float* __restrict__ shift, int C, float invCnt)
{
    int c = threadIdx.x;
    if (c < C) {
        float mu = sums[c] * invCnt;
        float var = ssqs[c] * invCnt - mu * mu;
        float sc = g[c] / sqrtf(var + 1e-5f);
        scale[c] = sc;
        shift[c] = be[c] - mu * sc;
    }
}

__global__ __launch_bounds__(256) void bnrelu_store_kernel(
    const float* __restrict__ y, const float* __restrict__ scale,
    const float* __restrict__ shift, float* __restrict__ out)
{
    int i = blockIdx.x * 256 + threadIdx.x;
    float4 v = ((const float4*)y)[i];
    int o = (i * 4) & (C2_ - 1);
    float4 sc = *(const float4*)(scale + o);
    float4 sh = *(const float4*)(shift + o);
    float4 r;
    r.x = fmaxf(fmaf(v.x, sc.x, sh.x), 0.0f);
    r.y = fmaxf(fmaf(v.y, sc.y, sh.y), 0.0f);
    r.z = fmaxf(fmaf(v.z, sc.z, sh.z), 0.0f);
    r.w = fmaxf(fmaf(v.w, sc.w, sh.w), 0.0f);
    ((float4*)out)[i] = r;
}

extern "C" void kernel_launch(void* const* d_in, const int* in_sizes, int n_in,
                              void* d_out, int out_size, void* d_ws, size_t ws_size,
                              hipStream_t stream)
{
    const float* xyz1    = (const float*)d_in[0];
    const float* xyz2    = (const float*)d_in[1];
    const float* points1 = (const float*)d_in[2];
    const float* points2 = (const float*)d_in[3];
    const float* w1  = (const float*)d_in[4];
    const float* b1  = (const float*)d_in[5];
    const float* g1  = (const float*)d_in[6];
    const float* be1 = (const float*)d_in[7];
    const float* w2  = (const float*)d_in[8];
    const float* b2  = (const float*)d_in[9];
    const float* g2  = (const float*)d_in[10];
    const float* be2 = (const float*)d_in[11];
    float* out = (float*)d_out;

    char* w = (char*)d_ws;
    float*          y2  = (float*)w;                             // 33,554,432
    unsigned short* y1b = (unsigned short*)(w + 33554432);       // 33,554,432
    float*          Zg  = (float*)(w + 67108864);                // 16,777,216
    unsigned short* p1b = (unsigned short*)(w + 83886080);       // 16,777,216
    unsigned short* p2b = (unsigned short*)(w + 100663296);      //  8,388,608
    char* tail = w + 109051904;
    int*   nidx = (int*)tail;                                    // 786,432
    float* nw   = (float*)(tail + 786432);                       // 786,432
    unsigned short* w1b = (unsigned short*)(tail + 1572864);     // 196,608
    unsigned short* w2b = (unsigned short*)(tail + 1769472);     // 65,536
    float* sum1   = (float*)(tail + 1835008);
    float* ssq1   = sum1 + 256;
    float* ssq1e  = ssq1 + 256;
    float* sum2   = ssq1e;                                       // alias naming
    float* ssq2   = sum2 + 128;
    float* scale1 = ssq2 + 128;
    float* shift1 = scale1 + 256;
    float* scale2 = shift1 + 256;
    float* shift2 = scale2 + 128;
    float4* pk    = (float4*)(tail + 1843200);                   // 262,144

    hipMemsetAsync(sum1, 0, (256 + 256 + 128 + 128) * sizeof(float), stream);

    cvtw_kernel<<<dim3((C1_ * CIN_ + C2_ * C1_ + 255) / 256), 256, 0, stream>>>(w1, w2, w1b, w2b);
    pack_kernel<<<dim3(B_ * S_ / 256), 256, 0, stream>>>(xyz2, pk);
    prep_kernel<<<dim3((ROWS_ * D1_ / 4 + B_ * S_ * D2_ / 4) / 256), 256, 0, stream>>>(
        points1, points2, p1b, p2b);

    nn3_kernel<<<dim3(N_ / 128, B_), 1024, 0, stream>>>(xyz1, pk, nidx, nw);

    zgemm_kernel<<<dim3(B_ * S_ / 128 * 2), 256, 0, stream>>>(p2b, w1b, Zg);

    gemm_p1_kernel<<<dim3(ROWS_ / 128 * 2), 256, 0, stream>>>(
        p1b, w1b, b1, nidx, nw, Zg, y1b, sum1, ssq1);
    finalize_kernel<<<1, 256, 0, stream>>>(sum1, ssq1, g1, be1, scale1, shift1, C1_, 1.0f / ROWS_);

    gemm2_kernel<<<dim3(ROWS_ / 128), 256, 0, stream>>>(
        y1b, w2b, b2, scale1, shift1, y2, sum2, ssq2);
    finalize_kernel<<<1, 256, 0, stream>>>(sum2, ssq2, g2, be2, scale2, shift2, C2_, 1.0f / ROWS_);

    bnrelu_store_kernel<<<dim3(ROWS_ * C2_ / 4 / 256), 256, 0, stream>>>(y2, scale2, shift2, out);
}

// Round 12
// 217.332 us; speedup vs baseline: 1.2208x; 1.2208x over previous
//
#include <hip/hip_runtime.h>
#include <hip/hip_bf16.h>

#define B_   8
#define N_   8192
#define S_   2048
#define D1_  128
#define D2_  256
#define CIN_ 384
#define C1_  256
#define C2_  128
#define ROWS_ (B_ * N_)   // 65536

typedef __attribute__((ext_vector_type(8))) short short8v;
typedef __attribute__((ext_vector_type(4))) float f32x4;
typedef __attribute__((ext_vector_type(16))) float f32x16;

__device__ inline unsigned short f2bf(float x) {
    __hip_bfloat16 h = __float2bfloat16(x);
    unsigned short u;
    __builtin_memcpy(&u, &h, 2);
    return u;
}
__device__ inline float bf2f(unsigned short u) {
    unsigned int x = ((unsigned int)u) << 16;
    float f;
    __builtin_memcpy(&f, &x, 4);
    return f;
}
__device__ inline unsigned int f2u(float x) { unsigned int u; __builtin_memcpy(&u, &x, 4); return u; }
__device__ inline float u2f(unsigned int u) { float x; __builtin_memcpy(&x, &u, 4); return x; }

// ---------------------------------------------------------------------------
// Pack xyz2 -> {x,y,z,r2} float4 (passed rounds 9-11; r2 bit-identical)
// ---------------------------------------------------------------------------
__global__ __launch_bounds__(256) void pack_kernel(
    const float* __restrict__ xyz2, float4* __restrict__ pk)
{
#pragma clang fp contract(off)
    int i = blockIdx.x * 256 + threadIdx.x;
    float a = xyz2[i * 3 + 0], c = xyz2[i * 3 + 1], d = xyz2[i * 3 + 2];
    float4 v; v.x = a; v.y = c; v.z = d; v.w = (a * a + c * c) + d * d;
    pk[i] = v;
}

// ---------------------------------------------------------------------------
// 3-NN two-pass, SMEM delivery (byte-identical to passing rounds 10/11, ~76µs)
// ---------------------------------------------------------------------------
__global__ __launch_bounds__(1024) void nn3_kernel(
    const float* __restrict__ xyz1, const float4* __restrict__ pk,
    int* __restrict__ nidx, float* __restrict__ nw)
{
#pragma clang fp contract(off)
    __shared__ unsigned int pa[8][128][3];
    __shared__ int   pb[8][128][2];
    __shared__ int   pc[8][128];
    __shared__ float fvv[128][3];
    const int tid = threadIdx.x;
    const int b = blockIdx.y;
    const int q = tid & 127;
    const int chunk = tid >> 7;
    const int s0 = chunk * 256;
    const unsigned s0u = __builtin_amdgcn_readfirstlane((unsigned)s0);
    const char* cp = (const char*)(pk + (size_t)b * S_) + (size_t)s0u * 16u;

    const int n = blockIdx.x * 128 + q;
    const float* p = xyz1 + ((size_t)b * N_ + n) * 3;
    const float px = p[0], py = p[1], pz = p[2];
    const float r1 = (px * px + py * py) + pz * pz;

    float e1 = 3.4e38f, e2 = 3.4e38f, e3 = 3.4e38f;
    for (int g = 0; g < 16; ++g) {
        f32x16 c0, c1, c2, c3;
        asm volatile("s_load_dwordx16 %0, %4, 0\n\t"
                     "s_load_dwordx16 %1, %4, 64\n\t"
                     "s_load_dwordx16 %2, %4, 128\n\t"
                     "s_load_dwordx16 %3, %4, 192\n\t"
                     "s_waitcnt lgkmcnt(0)"
                     : "=&s"(c0), "=&s"(c1), "=&s"(c2), "=&s"(c3)
                     : "s"(cp + (size_t)g * 256));
#pragma unroll
        for (int j = 0; j < 16; ++j) {
            float sx = (j < 4) ? c0[4*j+0] : (j < 8) ? c1[4*(j-4)+0] : (j < 12) ? c2[4*(j-8)+0] : c3[4*(j-12)+0];
            float sy = (j < 4) ? c0[4*j+1] : (j < 8) ? c1[4*(j-4)+1] : (j < 12) ? c2[4*(j-8)+1] : c3[4*(j-12)+1];
            float sz = (j < 4) ? c0[4*j+2] : (j < 8) ? c1[4*(j-4)+2] : (j < 12) ? c2[4*(j-8)+2] : c3[4*(j-12)+2];
            float sr = (j < 4) ? c0[4*j+3] : (j < 8) ? c1[4*(j-4)+3] : (j < 12) ? c2[4*(j-8)+3] : c3[4*(j-12)+3];
            float dot = (px * sx + py * sy) + pz * sz;
            float d = (r1 - 2.0f * dot) + sr;
            float n1 = fminf(e1, d);
            float n2 = __builtin_amdgcn_fmed3f(d, e1, e2);
            float n3 = __builtin_amdgcn_fmed3f(d, e2, e3);
            e1 = n1; e2 = n2; e3 = n3;
        }
    }
    pa[chunk][q][0] = f2u(e1); pa[chunk][q][1] = f2u(e2); pa[chunk][q][2] = f2u(e3);
    __syncthreads();

    float v1f = 0.f, v2f = 0.f, v3f = 0.f;
    if (tid < 128) {
        float m1 = u2f(pa[0][tid][0]), m2 = u2f(pa[0][tid][1]), m3 = u2f(pa[0][tid][2]);
#pragma unroll
        for (int c = 1; c < 8; ++c)
#pragma unroll
            for (int e = 0; e < 3; ++e) {
                float x = u2f(pa[c][tid][e]);
                float n1 = fminf(m1, x);
                float n2 = __builtin_amdgcn_fmed3f(x, m1, m2);
                float n3 = __builtin_amdgcn_fmed3f(x, m2, m3);
                m1 = n1; m2 = n2; m3 = n3;
            }
        v1f = m1; v2f = m2; v3f = m3;
        fvv[tid][0] = m1; fvv[tid][1] = m2; fvv[tid][2] = m3;
    }
    __syncthreads();
    const float t1 = fvv[q][0], t2 = fvv[q][1], t3 = fvv[q][2];

    int a1 = 0x7FFFFFFF, a2 = 0x7FFFFFFF, a3 = 0x7FFFFFFF;
    int b1 = 0x7FFFFFFF, b2 = 0x7FFFFFFF;
    int c1m = 0x7FFFFFFF;
    for (int g = 0; g < 16; ++g) {
        f32x16 c0, c1, c2, c3;
        asm volatile("s_load_dwordx16 %0, %4, 0\n\t"
                     "s_load_dwordx16 %1, %4, 64\n\t"
                     "s_load_dwordx16 %2, %4, 128\n\t"
                     "s_load_dwordx16 %3, %4, 192\n\t"
                     "s_waitcnt lgkmcnt(0)"
                     : "=&s"(c0), "=&s"(c1), "=&s"(c2), "=&s"(c3)
                     : "s"(cp + (size_t)g * 256));
#pragma unroll
        for (int j = 0; j < 16; ++j) {
            float sx = (j < 4) ? c0[4*j+0] : (j < 8) ? c1[4*(j-4)+0] : (j < 12) ? c2[4*(j-8)+0] : c3[4*(j-12)+0];
            float sy = (j < 4) ? c0[4*j+1] : (j < 8) ? c1[4*(j-4)+1] : (j < 12) ? c2[4*(j-8)+1] : c3[4*(j-12)+1];
            float sz = (j < 4) ? c0[4*j+2] : (j < 8) ? c1[4*(j-4)+2] : (j < 12) ? c2[4*(j-8)+2] : c3[4*(j-12)+2];
            float sr = (j < 4) ? c0[4*j+3] : (j < 8) ? c1[4*(j-4)+3] : (j < 12) ? c2[4*(j-8)+3] : c3[4*(j-12)+3];
            float dot = (px * sx + py * sy) + pz * sz;
            float d = (r1 - 2.0f * dot) + sr;
            if (d <= t3) {
                const int s = s0 + g * 16 + j;
                int u1 = (d == t1) ? s : 0x7FFFFFFF;
                int u2 = (d == t2) ? s : 0x7FFFFFFF;
                int na3 = min(a3, max(a2, u1));
                int na2 = min(a2, max(a1, u1));
                a1 = min(a1, u1); a2 = na2; a3 = na3;
                int nb2 = min(b2, max(b1, u2));
                b1 = min(b1, u2); b2 = nb2;
                c1m = (d == t3) ? min(c1m, s) : c1m;
            }
        }
    }
    pa[chunk][q][0] = (unsigned)a1; pa[chunk][q][1] = (unsigned)a2; pa[chunk][q][2] = (unsigned)a3;
    pb[chunk][q][0] = b1; pb[chunk][q][1] = b2;
    pc[chunk][q] = c1m;
    __syncthreads();

    if (tid < 128) {
        int A1 = 0x7FFFFFFF, A2 = 0x7FFFFFFF, A3 = 0x7FFFFFFF;
        int B1 = 0x7FFFFFFF, B2 = 0x7FFFFFFF;
        int C1m = 0x7FFFFFFF;
#pragma unroll
        for (int c = 0; c < 8; ++c) {
#pragma unroll
            for (int e = 0; e < 3; ++e) {
                int x = (int)pa[c][tid][e];
                int nA3 = min(A3, max(A2, x));
                int nA2 = min(A2, max(A1, x));
                A1 = min(A1, x); A2 = nA2; A3 = nA3;
            }
#pragma unroll
            for (int e = 0; e < 2; ++e) {
                int x = pb[c][tid][e];
                int nB2 = min(B2, max(B1, x));
                B1 = min(B1, x); B2 = nB2;
            }
            C1m = min(C1m, pc[c][tid]);
        }
        int j1 = A1, j2, j3;
        if (v2f == v1f) j2 = A2; else j2 = B1;
        if (v3f == v2f) j3 = (v2f == v1f) ? A3 : B2;
        else            j3 = C1m;
        float ra = 1.0f / (v1f + 1e-8f);
        float rb = 1.0f / (v2f + 1e-8f);
        float rc = 1.0f / (v3f + 1e-8f);
        float sum = (ra + rb) + rc;
        size_t o = ((size_t)b * N_ + blockIdx.x * 128 + tid) * 3;
        nidx[o + 0] = j1; nidx[o + 1] = j2; nidx[o + 2] = j3;
        nw[o + 0] = ra / sum; nw[o + 1] = rb / sum; nw[o + 2] = rc / sum;
    }
}

// weights -> bf16
__global__ void cvtw_kernel(const float* __restrict__ w1, const float* __restrict__ w2,
                            unsigned short* __restrict__ w1b, unsigned short* __restrict__ w2b)
{
    int i = blockIdx.x * 256 + threadIdx.x;
    if (i < C1_ * CIN_) w1b[i] = f2bf(w1[i]);
    else {
        int j = i - C1_ * CIN_;
        if (j < C2_ * C1_) w2b[j] = f2bf(w2[j]);
    }
}

// p1, p2 -> bf16
__global__ __launch_bounds__(256) void prep_kernel(
    const float* __restrict__ p1, const float* __restrict__ p2,
    unsigned short* __restrict__ p1b, unsigned short* __restrict__ p2b)
{
    int i = blockIdx.x * 256 + threadIdx.x;
    const int NP1 = ROWS_ * D1_ / 4;
    if (i < NP1) {
        float4 v = ((const float4*)p1)[i];
        ushort4 r; r.x = f2bf(v.x); r.y = f2bf(v.y); r.z = f2bf(v.z); r.w = f2bf(v.w);
        ((ushort4*)p1b)[i] = r;
    } else {
        int k = i - NP1;
        float4 v = ((const float4*)p2)[k];
        ushort4 r; r.x = f2bf(v.x); r.y = f2bf(v.y); r.z = f2bf(v.z); r.w = f2bf(v.w);
        ((ushort4*)p2b)[k] = r;
    }
}

// ---------------------------------------------------------------------------
// Z-GEMM: Z[r][col] = sum_k p2b[r][k] * w1[col][128+k]  (unchanged, validated)
// ---------------------------------------------------------------------------
__global__ __launch_bounds__(256) void zgemm_kernel(
    const unsigned short* __restrict__ A,   // p2b [16384][256]
    const unsigned short* __restrict__ W,   // w1b [256][384]
    float* __restrict__ Z)                  // [16384][256] f32
{
    __shared__ unsigned short As[4][128][8];
    __shared__ unsigned short Bs[4][128][8];
    const int tid = threadIdx.x;
    const int wave = tid >> 6, lane = tid & 63;
    const int chunkw = (blockIdx.x & 7) * (gridDim.x >> 3) + (blockIdx.x >> 3);
    const int r0 = (chunkw >> 1) * 128;
    const int n0 = (chunkw & 1) * 128;
    const int wr = wave >> 1, wc = wave & 1;
    const int kh = lane >> 4, l16 = lane & 15;

    f32x4 acc[4][4];
#pragma unroll
    for (int m = 0; m < 4; ++m)
#pragma unroll
        for (int n = 0; n < 4; ++n)
            acc[m][n] = (f32x4){0.f, 0.f, 0.f, 0.f};

    const int slotbase = wave * 64;
    for (int k0 = 0; k0 < 256; k0 += 32) {
        __syncthreads();
#pragma unroll
        for (int p = 0; p < 2; ++p) {
            const int sb = p * 256 + slotbase;
            const int s = sb + lane;
            const int kg = s >> 7, i = s & 127;
            const unsigned short* gA = A + (size_t)(r0 + i) * 256 + k0 + kg * 8;
            const unsigned short* gB = W + (size_t)(n0 + i) * CIN_ + D1_ + k0 + kg * 8;
            __builtin_amdgcn_global_load_lds(
                (const __attribute__((address_space(1))) void*)gA,
                (__attribute__((address_space(3))) void*)(&As[0][0][0] + (size_t)sb * 8),
                16, 0, 0);
            __builtin_amdgcn_global_load_lds(
                (const __attribute__((address_space(1))) void*)gB,
                (__attribute__((address_space(3))) void*)(&Bs[0][0][0] + (size_t)sb * 8),
                16, 0, 0);
        }
        __syncthreads();

        short8v af[4], bf[4];
#pragma unroll
        for (int m = 0; m < 4; ++m)
            af[m] = *(const short8v*)&As[kh][wr * 64 + m * 16 + l16][0];
#pragma unroll
        for (int n = 0; n < 4; ++n)
            bf[n] = *(const short8v*)&Bs[kh][wc * 64 + n * 16 + l16][0];
#pragma unroll
        for (int m = 0; m < 4; ++m)
#pragma unroll
            for (int n = 0; n < 4; ++n)
                acc[m][n] = __builtin_amdgcn_mfma_f32_16x16x32_bf16(
                    af[m], bf[n], acc[m][n], 0, 0, 0);
    }

#pragma unroll
    for (int n = 0; n < 4; ++n) {
        const int col = n0 + wc * 64 + n * 16 + l16;
#pragma unroll
        for (int m = 0; m < 4; ++m) {
            const int rowb = r0 + wr * 64 + m * 16 + kh * 4;
#pragma unroll
            for (int j = 0; j < 4; ++j)
                Z[(size_t)(rowb + j) * 256 + col] = acc[m][n][j];
        }
    }
}

// ---------------------------------------------------------------------------
// interp over Z (coalesced a1build shape, proven): zi[row][c] =
//   sum_k nw_k * Z[b][idx_k][c] + bias[c], bf16 out. XCD batch affinity.
// ---------------------------------------------------------------------------
__global__ __launch_bounds__(256) void interpz_kernel(
    const float* __restrict__ Zg, const int* __restrict__ nidx,
    const float* __restrict__ nw, const float* __restrict__ bias,
    unsigned short* __restrict__ zi)
{
    const int row = (blockIdx.x & 7) * N_ + (blockIdx.x >> 3);  // batch = xcd
    const int c = threadIdx.x;
    const int b = row >> 13;
    const int i0 = nidx[row * 3 + 0], i1 = nidx[row * 3 + 1], i2 = nidx[row * 3 + 2];
    const float w0 = nw[row * 3 + 0], w1 = nw[row * 3 + 1], w2 = nw[row * 3 + 2];
    const float* Zb = Zg + (size_t)b * S_ * 256;
    float v = Zb[(size_t)i0 * 256 + c] * w0
            + Zb[(size_t)i1 * 256 + c] * w1
            + Zb[(size_t)i2 * 256 + c] * w2 + bias[c];
    zi[(size_t)row * 256 + c] = f2bf(v);
}

// ---------------------------------------------------------------------------
// GEMM1': y1 = p1b @ W1a^T + zi  (K=128, proven 16KB-LDS loop; coalesced zi
// add in epilogue). Fused BN-stats. Output bf16.
// ---------------------------------------------------------------------------
__global__ __launch_bounds__(256) void gemm_p1_kernel(
    const unsigned short* __restrict__ A,   // p1b [65536][128]
    const unsigned short* __restrict__ W,   // w1b [256][384] (cols 0..127)
    const unsigned short* __restrict__ zi,  // [65536][256] bf16 (incl bias)
    unsigned short* __restrict__ out,       // y1b
    float* __restrict__ sums, float* __restrict__ ssqs)
{
    __shared__ unsigned short As[4][128][8];
    __shared__ unsigned short Bs[4][128][8];
    __shared__ float csum[128], csq[128];
    const int tid = threadIdx.x;
    const int wave = tid >> 6, lane = tid & 63;
    const int chunkw = (blockIdx.x & 7) * (gridDim.x >> 3) + (blockIdx.x >> 3);
    const int r0 = (chunkw >> 1) * 128;
    const int n0 = (chunkw & 1) * 128;
    const int wr = wave >> 1, wc = wave & 1;
    const int kh = lane >> 4, l16 = lane & 15;

    if (tid < 128) { csum[tid] = 0.f; csq[tid] = 0.f; }

    f32x4 acc[4][4];
#pragma unroll
    for (int m = 0; m < 4; ++m)
#pragma unroll
        for (int n = 0; n < 4; ++n)
            acc[m][n] = (f32x4){0.f, 0.f, 0.f, 0.f};

    const int slotbase = wave * 64;
    for (int k0 = 0; k0 < D1_; k0 += 32) {
        __syncthreads();
#pragma unroll
        for (int p = 0; p < 2; ++p) {
            const int sb = p * 256 + slotbase;
            const int s = sb + lane;
            const int kg = s >> 7, i = s & 127;
            const unsigned short* gA = A + (size_t)(r0 + i) * D1_ + k0 + kg * 8;
            const unsigned short* gB = W + (size_t)(n0 + i) * CIN_ + k0 + kg * 8;
            __builtin_amdgcn_global_load_lds(
                (const __attribute__((address_space(1))) void*)gA,
                (__attribute__((address_space(3))) void*)(&As[0][0][0] + (size_t)sb * 8),
                16, 0, 0);
            __builtin_amdgcn_global_load_lds(
                (const __attribute__((address_space(1))) void*)gB,
                (__attribute__((address_space(3))) void*)(&Bs[0][0][0] + (size_t)sb * 8),
                16, 0, 0);
        }
        __syncthreads();

        short8v af[4], bf[4];
#pragma unroll
        for (int m = 0; m < 4; ++m)
            af[m] = *(const short8v*)&As[kh][wr * 64 + m * 16 + l16][0];
#pragma unroll
        for (int n = 0; n < 4; ++n)
            bf[n] = *(const short8v*)&Bs[kh][wc * 64 + n * 16 + l16][0];
#pragma unroll
        for (int m = 0; m < 4; ++m)
#pragma unroll
            for (int n = 0; n < 4; ++n)
                acc[m][n] = __builtin_amdgcn_mfma_f32_16x16x32_bf16(
                    af[m], bf[n], acc[m][n], 0, 0, 0);
    }

    // epilogue: + zi (coalesced), stats, store
#pragma unroll
    for (int n = 0; n < 4; ++n) {
        const int cl = wc * 64 + n * 16 + l16;
        const int col = n0 + cl;
        float s = 0.f, qs = 0.f;
#pragma unroll
        for (int m = 0; m < 4; ++m) {
            const int rowb = r0 + wr * 64 + m * 16 + kh * 4;
#pragma unroll
            for (int j = 0; j < 4; ++j) {
                const float v = acc[m][n][j]
                              + bf2f(zi[(size_t)(rowb + j) * C1_ + col]);
                s += v; qs += v * v;
                out[(size_t)(rowb + j) * C1_ + col] = f2bf(v);
            }
        }
        atomicAdd(&csum[cl], s);
        atomicAdd(&csq[cl], qs);
    }
    __syncthreads();
    if (tid < 128) {
        atomicAdd(&sums[n0 + tid], csum[tid]);
        atomicAdd(&ssqs[n0 + tid], csq[tid]);
    }
}

// ---------------------------------------------------------------------------
// GEMM2 (unchanged from passing round 11): A = relu(y1b*scale+shift),
// reg-staged; fused bias + stats. Output f32.
// ---------------------------------------------------------------------------
__global__ __launch_bounds__(256) void gemm2_kernel(
    const unsigned short* __restrict__ Abf,
    const unsigned short* __restrict__ W,
    const float* __restrict__ bias,
    const float* __restrict__ scale, const float* __restrict__ shift,
    float* __restrict__ outf,
    float* __restrict__ sums, float* __restrict__ ssqs)
{
    __shared__ unsigned short As[4][128][8];
    __shared__ unsigned short Bs[4][128][8];
    __shared__ float csum[128], csq[128];
    const int tid = threadIdx.x;
    const int wave = tid >> 6, lane = tid & 63;
    const int chunkw = (blockIdx.x & 7) * (gridDim.x >> 3) + (blockIdx.x >> 3);
    const int r0 = chunkw * 128;
    const int n0 = 0;
    const int wr = wave >> 1, wc = wave & 1;
    const int kh = lane >> 4, l16 = lane & 15;

    if (tid < 128) { csum[tid] = 0.f; csq[tid] = 0.f; }

    f32x4 acc[4][4];
#pragma unroll
    for (int m = 0; m < 4; ++m)
#pragma unroll
        for (int n = 0; n < 4; ++n)
            acc[m][n] = (f32x4){0.f, 0.f, 0.f, 0.f};

    const int slotbase = wave * 64;
    int rowA[2];
#pragma unroll
    for (int p = 0; p < 2; ++p)
        rowA[p] = r0 + ((p * 256 + slotbase + lane) & 127);

    for (int k0 = 0; k0 < C1_; k0 += 32) {
        __syncthreads();
#pragma unroll
        for (int p = 0; p < 2; ++p) {
            const int sb = p * 256 + slotbase;
            const int s = sb + lane;
            const int kg = s >> 7, i = s & 127;
            const unsigned short* gB = W + (size_t)(n0 + i) * C1_ + k0 + kg * 8;
            __builtin_amdgcn_global_load_lds(
                (const __attribute__((address_space(1))) void*)gB,
                (__attribute__((address_space(3))) void*)(&Bs[0][0][0] + (size_t)sb * 8),
                16, 0, 0);
            const int c0 = k0 + kg * 8;
            short8v v = *(const short8v*)(Abf + (size_t)rowA[p] * C1_ + c0);
            float4 sca = *(const float4*)(scale + c0);
            float4 scb = *(const float4*)(scale + c0 + 4);
            float4 sha = *(const float4*)(shift + c0);
            float4 shb = *(const float4*)(shift + c0 + 4);
            float sc[8] = {sca.x, sca.y, sca.z, sca.w, scb.x, scb.y, scb.z, scb.w};
            float sh[8] = {sha.x, sha.y, sha.z, sha.w, shb.x, shb.y, shb.z, shb.w};
            short8v r;
#pragma unroll
            for (int j = 0; j < 8; ++j) {
                float f = bf2f((unsigned short)v[j]);
                f = fmaxf(fmaf(f, sc[j], sh[j]), 0.0f);
                r[j] = (short)f2bf(f);
            }
            *(short8v*)&As[kg][s & 127][0] = r;
        }
        __syncthreads();

        short8v af[4], bf[4];
#pragma unroll
        for (int m = 0; m < 4; ++m)
            af[m] = *(const short8v*)&As[kh][wr * 64 + m * 16 + l16][0];
#pragma unroll
        for (int n = 0; n < 4; ++n)
            bf[n] = *(const short8v*)&Bs[kh][wc * 64 + n * 16 + l16][0];
#pragma unroll
        for (int m = 0; m < 4; ++m)
#pragma unroll
            for (int n = 0; n < 4; ++n)
                acc[m][n] = __builtin_amdgcn_mfma_f32_16x16x32_bf16(
                    af[m], bf[n], acc[m][n], 0, 0, 0);
    }

#pragma unroll
    for (int n = 0; n < 4; ++n) {
        const int cl = wc * 64 + n * 16 + l16;
        const int col = n0 + cl;
        const float bv = bias[col];
        float s = 0.f, qs = 0.f;
#pragma unroll
        for (int m = 0; m < 4; ++m) {
            const int rowb = r0 + wr * 64 + m * 16 + kh * 4;
#pragma unroll
            for (int j = 0; j < 4; ++j) {
                const float v = acc[m][n][j] + bv;
                s += v; qs += v * v;
                outf[(size_t)(rowb + j) * C2_ + col] = v;
            }
        }
        atomicAdd(&csum[cl], s);
        atomicAdd(&csq[cl], qs);
    }
    __syncthreads();
    if (tid < 128) {
        atomicAdd(&sums[n0 + tid], csum[tid]);
        atomicAdd(&ssqs[n0 + tid], csq[tid]);
    }
}

__global__ void finalize_kernel(const float* __restrict__ sums,
                                const float* __restrict__ ssqs,
                                const float* __restrict__ g,
                                const float* __restrict__ be,
                                float* __restrict__ scale,
                                float* __restrict__ shift, int C, float invCnt)
{
    int c = threadIdx.x;
    if (c < C) {
        float mu = sums[c] * invCnt;
        float var = ssqs[c] * invCnt - mu * mu;
        float sc = g[c] / sqrtf(var + 1e-5f);
        scale[c] = sc;
        shift[c] = be[c] - mu * sc;
    }
}

__global__ __launch_bounds__(256) void bnrelu_store_kernel(
    const float* __restrict__ y, const float* __restrict__ scale,
    const float* __restrict__ shift, float* __restrict__ out)
{
    int i = blockIdx.x * 256 + threadIdx.x;
    float4 v = ((const float4*)y)[i];
    int o = (i * 4) & (C2_ - 1);
    float4 sc = *(const float4*)(scale + o);
    float4 sh = *(const float4*)(shift + o);
    float4 r;
    r.x = fmaxf(fmaf(v.x, sc.x, sh.x), 0.0f);
    r.y = fmaxf(fmaf(v.y, sc.y, sh.y), 0.0f);
    r.z = fmaxf(fmaf(v.z, sc.z, sh.z), 0.0f);
    r.w = fmaxf(fmaf(v.w, sc.w, sh.w), 0.0f);
    ((float4*)out)[i] = r;
}

extern "C" void kernel_launch(void* const* d_in, const int* in_sizes, int n_in,
                              void* d_out, int out_size, void* d_ws, size_t ws_size,
                              hipStream_t stream)
{
    const float* xyz1    = (const float*)d_in[0];
    const float* xyz2    = (const float*)d_in[1];
    const float* points1 = (const float*)d_in[2];
    const float* points2 = (const float*)d_in[3];
    const float* w1  = (const float*)d_in[4];
    const float* b1  = (const float*)d_in[5];
    const float* g1  = (const float*)d_in[6];
    const float* be1 = (const float*)d_in[7];
    const float* w2  = (const float*)d_in[8];
    const float* b2  = (const float*)d_in[9];
    const float* g2  = (const float*)d_in[10];
    const float* be2 = (const float*)d_in[11];
    float* out = (float*)d_out;

    char* w = (char*)d_ws;
    // region0: zi (bf16, consumed by gemm_p1) then y2 (f32, written by gemm2)
    unsigned short* zi  = (unsigned short*)w;                    // 33,554,432
    float*          y2  = (float*)w;                             // 33,554,432
    unsigned short* y1b = (unsigned short*)(w + 33554432);       // 33,554,432
    float*          Zg  = (float*)(w + 67108864);                // 16,777,216
    unsigned short* p1b = (unsigned short*)(w + 83886080);       // 16,777,216
    unsigned short* p2b = (unsigned short*)(w + 100663296);      //  8,388,608
    char* tail = w + 109051904;
    int*   nidx = (int*)tail;                                    // 786,432
    float* nw   = (float*)(tail + 786432);                       // 786,432
    unsigned short* w1b = (unsigned short*)(tail + 1572864);     // 196,608
    unsigned short* w2b = (unsigned short*)(tail + 1769472);     // 65,536
    float* sum1   = (float*)(tail + 1835008);
    float* ssq1   = sum1 + 256;
    float* sum2   = ssq1 + 256;
    float* ssq2   = sum2 + 128;
    float* scale1 = ssq2 + 128;
    float* shift1 = scale1 + 256;
    float* scale2 = shift1 + 256;
    float* shift2 = scale2 + 128;
    float4* pk    = (float4*)(tail + 1843200);                   // 262,144

    hipMemsetAsync(sum1, 0, (256 + 256 + 128 + 128) * sizeof(float), stream);

    cvtw_kernel<<<dim3((C1_ * CIN_ + C2_ * C1_ + 255) / 256), 256, 0, stream>>>(w1, w2, w1b, w2b);
    pack_kernel<<<dim3(B_ * S_ / 256), 256, 0, stream>>>(xyz2, pk);
    prep_kernel<<<dim3((ROWS_ * D1_ / 4 + B_ * S_ * D2_ / 4) / 256), 256, 0, stream>>>(
        points1, points2, p1b, p2b);

    nn3_kernel<<<dim3(N_ / 128, B_), 1024, 0, stream>>>(xyz1, pk, nidx, nw);

    zgemm_kernel<<<dim3(B_ * S_ / 128 * 2), 256, 0, stream>>>(p2b, w1b, Zg);

    interpz_kernel<<<dim3(ROWS_), 256, 0, stream>>>(Zg, nidx, nw, b1, zi);

    gemm_p1_kernel<<<dim3(ROWS_ / 128 * 2), 256, 0, stream>>>(
        p1b, w1b, zi, y1b, sum1, ssq1);
    finalize_kernel<<<1, 256, 0, stream>>>(sum1, ssq1, g1, be1, scale1, shift1, C1_, 1.0f / ROWS_);

    gemm2_kernel<<<dim3(ROWS_ / 128), 256, 0, stream>>>(
        y1b, w2b, b2, scale1, shift1, y2, sum2, ssq2);
    finalize_kernel<<<1, 256, 0, stream>>>(sum2, ssq2, g2, be2, scale2, shift2, C2_, 1.0f / ROWS_);

    bnrelu_store_kernel<<<dim3(ROWS_ * C2_ / 4 / 256), 256, 0, stream>>>(y2, scale2, shift2, out);
}

// Round 13
// 209.387 us; speedup vs baseline: 1.2671x; 1.0379x over previous
//
#include <hip/hip_runtime.h>
#include <hip/hip_bf16.h>

#define B_   8
#define N_   8192
#define S_   2048
#define D1_  128
#define D2_  256
#define CIN_ 384
#define C1_  256
#define C2_  128
#define ROWS_ (B_ * N_)   // 65536

typedef __attribute__((ext_vector_type(8))) short short8v;
typedef __attribute__((ext_vector_type(4))) float f32x4;
typedef __attribute__((ext_vector_type(16))) float f32x16;

__device__ inline unsigned short f2bf(float x) {
    __hip_bfloat16 h = __float2bfloat16(x);
    unsigned short u;
    __builtin_memcpy(&u, &h, 2);
    return u;
}
__device__ inline float bf2f(unsigned short u) {
    unsigned int x = ((unsigned int)u) << 16;
    float f;
    __builtin_memcpy(&f, &x, 4);
    return f;
}
__device__ inline unsigned int f2u(float x) { unsigned int u; __builtin_memcpy(&u, &x, 4); return u; }
__device__ inline float u2f(unsigned int u) { float x; __builtin_memcpy(&x, &u, 4); return x; }

// ---------------------------------------------------------------------------
// Pack xyz2 -> {x,y,z,r2} float4 (passed rounds 9-12; r2 bit-identical)
// ---------------------------------------------------------------------------
__global__ __launch_bounds__(256) void pack_kernel(
    const float* __restrict__ xyz2, float4* __restrict__ pk)
{
#pragma clang fp contract(off)
    int i = blockIdx.x * 256 + threadIdx.x;
    float a = xyz2[i * 3 + 0], c = xyz2[i * 3 + 1], d = xyz2[i * 3 + 2];
    float4 v; v.x = a; v.y = c; v.z = d; v.w = (a * a + c * c) + d * d;
    pk[i] = v;
}

// ---------------------------------------------------------------------------
// 3-NN SINGLE-PASS: track (value, index) sorted triple inline.
// Values via fmin/fmed3 (identical values as the passing two-pass version);
// indices routed by 3 strict-< compares + 5 cndmask. Strict < on d ==
// lexicographic (d, idx) lower-index-wins == top_k tie-break, since scan
// order and chunk-merge order are index-ascending. SMEM candidate delivery
// (proven), now 16 waits total (was 32 across two passes).
// Distance arithmetic bit-identical to all passing rounds.
// ---------------------------------------------------------------------------
__global__ __launch_bounds__(1024) void nn3_kernel(
    const float* __restrict__ xyz1, const float4* __restrict__ pk,
    int* __restrict__ nidx, float* __restrict__ nw)
{
#pragma clang fp contract(off)
    __shared__ unsigned int pv[8][128][3];   // partial top-3 value bits
    __shared__ int          pi[8][128][3];   // partial top-3 indices
    const int tid = threadIdx.x;
    const int b = blockIdx.y;
    const int q = tid & 127;
    const int chunk = tid >> 7;              // wave-uniform (128-aligned)
    const int s0 = chunk * 256;
    const unsigned s0u = __builtin_amdgcn_readfirstlane((unsigned)s0);
    const char* cp = (const char*)(pk + (size_t)b * S_) + (size_t)s0u * 16u;

    const int n = blockIdx.x * 128 + q;
    const float* p = xyz1 + ((size_t)b * N_ + n) * 3;
    const float px = p[0], py = p[1], pz = p[2];
    const float r1 = (px * px + py * py) + pz * pz;

    float e1 = 3.4e38f, e2 = 3.4e38f, e3 = 3.4e38f;
    int i1 = 0x7FFFFFFF, i2 = 0x7FFFFFFF, i3 = 0x7FFFFFFF;
    for (int g = 0; g < 16; ++g) {
        f32x16 c0, c1, c2, c3;
        asm volatile("s_load_dwordx16 %0, %4, 0\n\t"
                     "s_load_dwordx16 %1, %4, 64\n\t"
                     "s_load_dwordx16 %2, %4, 128\n\t"
                     "s_load_dwordx16 %3, %4, 192\n\t"
                     "s_waitcnt lgkmcnt(0)"
                     : "=&s"(c0), "=&s"(c1), "=&s"(c2), "=&s"(c3)
                     : "s"(cp + (size_t)g * 256));
#pragma unroll
        for (int j = 0; j < 16; ++j) {
            float sx = (j < 4) ? c0[4*j+0] : (j < 8) ? c1[4*(j-4)+0] : (j < 12) ? c2[4*(j-8)+0] : c3[4*(j-12)+0];
            float sy = (j < 4) ? c0[4*j+1] : (j < 8) ? c1[4*(j-4)+1] : (j < 12) ? c2[4*(j-8)+1] : c3[4*(j-12)+1];
            float sz = (j < 4) ? c0[4*j+2] : (j < 8) ? c1[4*(j-4)+2] : (j < 12) ? c2[4*(j-8)+2] : c3[4*(j-12)+2];
            float sr = (j < 4) ? c0[4*j+3] : (j < 8) ? c1[4*(j-4)+3] : (j < 12) ? c2[4*(j-8)+3] : c3[4*(j-12)+3];
            float dot = (px * sx + py * sy) + pz * sz;
            float d = (r1 - 2.0f * dot) + sr;
            const int s = s0 + g * 16 + j;
            bool lt1 = d < e1, lt2 = d < e2, lt3 = d < e3;
            float n1 = fminf(e1, d);
            float n2 = __builtin_amdgcn_fmed3f(d, e1, e2);
            float n3 = __builtin_amdgcn_fmed3f(d, e2, e3);
            int ni1 = lt1 ? s : i1;
            int ni2 = lt1 ? i1 : (lt2 ? s : i2);
            int ni3 = lt2 ? i2 : (lt3 ? s : i3);
            e1 = n1; e2 = n2; e3 = n3;
            i1 = ni1; i2 = ni2; i3 = ni3;
        }
    }
    pv[chunk][q][0] = f2u(e1); pv[chunk][q][1] = f2u(e2); pv[chunk][q][2] = f2u(e3);
    pi[chunk][q][0] = i1; pi[chunk][q][1] = i2; pi[chunk][q][2] = i3;
    __syncthreads();

    if (tid < 128) {
        float m1 = u2f(pv[0][tid][0]), m2 = u2f(pv[0][tid][1]), m3 = u2f(pv[0][tid][2]);
        int j1 = pi[0][tid][0], j2 = pi[0][tid][1], j3 = pi[0][tid][2];
#pragma unroll
        for (int c = 1; c < 8; ++c) {
#pragma unroll
            for (int e = 0; e < 3; ++e) {
                float x = u2f(pv[c][tid][e]);
                int   xi = pi[c][tid][e];
                bool lt1 = x < m1, lt2 = x < m2, lt3 = x < m3;
                float n1 = fminf(m1, x);
                float n2 = __builtin_amdgcn_fmed3f(x, m1, m2);
                float n3 = __builtin_amdgcn_fmed3f(x, m2, m3);
                int nj1 = lt1 ? xi : j1;
                int nj2 = lt1 ? j1 : (lt2 ? xi : j2);
                int nj3 = lt2 ? j2 : (lt3 ? xi : j3);
                m1 = n1; m2 = n2; m3 = n3;
                j1 = nj1; j2 = nj2; j3 = nj3;
            }
        }
        float ra = 1.0f / (m1 + 1e-8f);
        float rb = 1.0f / (m2 + 1e-8f);
        float rc = 1.0f / (m3 + 1e-8f);
        float sum = (ra + rb) + rc;
        size_t o = ((size_t)b * N_ + blockIdx.x * 128 + tid) * 3;
        nidx[o + 0] = j1; nidx[o + 1] = j2; nidx[o + 2] = j3;
        nw[o + 0] = ra / sum; nw[o + 1] = rb / sum; nw[o + 2] = rc / sum;
    }
}

// weights -> bf16
__global__ void cvtw_kernel(const float* __restrict__ w1, const float* __restrict__ w2,
                            unsigned short* __restrict__ w1b, unsigned short* __restrict__ w2b)
{
    int i = blockIdx.x * 256 + threadIdx.x;
    if (i < C1_ * CIN_) w1b[i] = f2bf(w1[i]);
    else {
        int j = i - C1_ * CIN_;
        if (j < C2_ * C1_) w2b[j] = f2bf(w2[j]);
    }
}

// ---------------------------------------------------------------------------
// GEMM1 (MODE2) with DEFERRED A-GATHER (T14-lite): step k+1's gather loads
// are issued BEFORE the MFMA block of step k and converted AFTER it, so the
// compiler's vmcnt wait lands post-MFMA and ~16 MFMAs hide the L2 latency.
// B staged via global_load_lds as in the proven r10 version. Fused bias +
// BN-stats epilogue. Output bf16.
// ---------------------------------------------------------------------------
__global__ __launch_bounds__(256) void gemm1_kernel(
    const unsigned short* __restrict__ W,    // w1b [256][384]
    const float* __restrict__ bias,
    const float* __restrict__ p1,
    const float* __restrict__ p2,
    const int* __restrict__ nidx,
    const float* __restrict__ nw,
    unsigned short* __restrict__ out,        // y1b [65536][256]
    float* __restrict__ sums, float* __restrict__ ssqs)
{
    __shared__ unsigned short As[4][128][8];
    __shared__ unsigned short Bs[4][128][8];
    __shared__ float csum[128], csq[128];
    const int tid = threadIdx.x;
    const int wave = tid >> 6, lane = tid & 63;
    const int chunkw = (blockIdx.x & 7) * (gridDim.x >> 3) + (blockIdx.x >> 3);
    const int r0 = (chunkw >> 1) * 128;
    const int n0 = (chunkw & 1) * 128;
    const int wr = wave >> 1, wc = wave & 1;
    const int kh = lane >> 4, l16 = lane & 15;

    if (tid < 128) { csum[tid] = 0.f; csq[tid] = 0.f; }

    f32x4 acc[4][4];
#pragma unroll
    for (int m = 0; m < 4; ++m)
#pragma unroll
        for (int n = 0; n < 4; ++n)
            acc[m][n] = (f32x4){0.f, 0.f, 0.f, 0.f};

    const int slotbase = wave * 64;
    // per-slot staging metadata
    int ip[2], kgp[2], rowA[2];
    int gj0[2], gj1[2], gj2[2];
    float gw0[2], gw1[2], gw2[2];
    const float* p2b = p2 + (size_t)(r0 >> 13) * S_ * D2_;   // block-uniform batch
#pragma unroll
    for (int pp = 0; pp < 2; ++pp) {
        const int s = pp * 256 + slotbase + lane;
        ip[pp] = s & 127;
        kgp[pp] = s >> 7;
        rowA[pp] = r0 + ip[pp];
        gj0[pp] = nidx[rowA[pp] * 3 + 0];
        gj1[pp] = nidx[rowA[pp] * 3 + 1];
        gj2[pp] = nidx[rowA[pp] * 3 + 2];
        gw0[pp] = nw[rowA[pp] * 3 + 0];
        gw1[pp] = nw[rowA[pp] * 3 + 1];
        gw2[pp] = nw[rowA[pp] * 3 + 2];
    }

    float4 ga[2][3], gb[2][3];   // in-flight gather data [slot][row]
    short8v aregs[2];

    // issue loads for step kk (no wait)
    auto issue = [&](int kk) {
#pragma unroll
        for (int pp = 0; pp < 2; ++pp) {
            const int c0 = kk + kgp[pp] * 8;
            if (kk < D1_) {
                const float* qq = p1 + (size_t)rowA[pp] * D1_ + c0;
                ga[pp][0] = *(const float4*)qq;
                gb[pp][0] = *(const float4*)(qq + 4);
            } else {
                const int cc = c0 - D1_;
                const float* q0 = p2b + (size_t)gj0[pp] * D2_ + cc;
                const float* q1 = p2b + (size_t)gj1[pp] * D2_ + cc;
                const float* q2 = p2b + (size_t)gj2[pp] * D2_ + cc;
                ga[pp][0] = *(const float4*)q0; gb[pp][0] = *(const float4*)(q0 + 4);
                ga[pp][1] = *(const float4*)q1; gb[pp][1] = *(const float4*)(q1 + 4);
                ga[pp][2] = *(const float4*)q2; gb[pp][2] = *(const float4*)(q2 + 4);
            }
        }
    };
    // convert loaded data for step kk into aregs
    auto convert = [&](int kk) {
#pragma unroll
        for (int pp = 0; pp < 2; ++pp) {
            short8v r;
            if (kk < D1_) {
                float t[8] = {ga[pp][0].x, ga[pp][0].y, ga[pp][0].z, ga[pp][0].w,
                              gb[pp][0].x, gb[pp][0].y, gb[pp][0].z, gb[pp][0].w};
#pragma unroll
                for (int j = 0; j < 8; ++j) r[j] = (short)f2bf(t[j]);
            } else {
                float a0[8] = {ga[pp][0].x, ga[pp][0].y, ga[pp][0].z, ga[pp][0].w,
                               gb[pp][0].x, gb[pp][0].y, gb[pp][0].z, gb[pp][0].w};
                float a1[8] = {ga[pp][1].x, ga[pp][1].y, ga[pp][1].z, ga[pp][1].w,
                               gb[pp][1].x, gb[pp][1].y, gb[pp][1].z, gb[pp][1].w};
                float a2[8] = {ga[pp][2].x, ga[pp][2].y, ga[pp][2].z, ga[pp][2].w,
                               gb[pp][2].x, gb[pp][2].y, gb[pp][2].z, gb[pp][2].w};
                const float w0 = gw0[pp], w1 = gw1[pp], w2 = gw2[pp];
#pragma unroll
                for (int j = 0; j < 8; ++j)
                    r[j] = (short)f2bf(a0[j] * w0 + a1[j] * w1 + a2[j] * w2);
            }
            aregs[pp] = r;
        }
    };

    // prologue: prepare step 0 fully
    issue(0);
    convert(0);

    for (int k0 = 0; k0 < CIN_; k0 += 32) {
        __syncthreads();
#pragma unroll
        for (int pp = 0; pp < 2; ++pp) {
            const int sb = pp * 256 + slotbase;
            const int s = sb + lane;
            const int i = s & 127;
            const unsigned short* gB = W + (size_t)(n0 + i) * CIN_ + k0 + (s >> 7) * 8;
            __builtin_amdgcn_global_load_lds(
                (const __attribute__((address_space(1))) void*)gB,
                (__attribute__((address_space(3))) void*)(&Bs[0][0][0] + (size_t)sb * 8),
                16, 0, 0);
            *(short8v*)&As[kgp[pp]][ip[pp]][0] = aregs[pp];
        }
        __syncthreads();

        const int kn = k0 + 32;
        if (kn < CIN_) issue(kn);          // loads in flight during MFMA

        short8v af[4], bf[4];
#pragma unroll
        for (int m = 0; m < 4; ++m)
            af[m] = *(const short8v*)&As[kh][wr * 64 + m * 16 + l16][0];
#pragma unroll
        for (int n = 0; n < 4; ++n)
            bf[n] = *(const short8v*)&Bs[kh][wc * 64 + n * 16 + l16][0];
#pragma unroll
        for (int m = 0; m < 4; ++m)
#pragma unroll
            for (int n = 0; n < 4; ++n)
                acc[m][n] = __builtin_amdgcn_mfma_f32_16x16x32_bf16(
                    af[m], bf[n], acc[m][n], 0, 0, 0);

        if (kn < CIN_) convert(kn);        // vmcnt wait lands here, post-MFMA
    }

#pragma unroll
    for (int n = 0; n < 4; ++n) {
        const int cl = wc * 64 + n * 16 + l16;
        const int col = n0 + cl;
        const float bv = bias[col];
        float s = 0.f, qs = 0.f;
#pragma unroll
        for (int m = 0; m < 4; ++m) {
            const int rowb = r0 + wr * 64 + m * 16 + kh * 4;
#pragma unroll
            for (int j = 0; j < 4; ++j) {
                const float v = acc[m][n][j] + bv;
                s += v; qs += v * v;
                out[(size_t)(rowb + j) * C1_ + col] = f2bf(v);
            }
        }
        atomicAdd(&csum[cl], s);
        atomicAdd(&csq[cl], qs);
    }
    __syncthreads();
    if (tid < 128) {
        atomicAdd(&sums[n0 + tid], csum[tid]);
        atomicAdd(&ssqs[n0 + tid], csq[tid]);
    }
}

// ---------------------------------------------------------------------------
// GEMM2 (MODE1, byte-identical logic to passing rounds 10-12):
// A = relu(y1b*scale+shift) reg-staged; fused bias + stats. Output f32.
// ---------------------------------------------------------------------------
__global__ __launch_bounds__(256) void gemm2_kernel(
    const unsigned short* __restrict__ Abf,
    const unsigned short* __restrict__ W,
    const float* __restrict__ bias,
    const float* __restrict__ scale, const float* __restrict__ shift,
    float* __restrict__ outf,
    float* __restrict__ sums, float* __restrict__ ssqs)
{
    __shared__ unsigned short As[4][128][8];
    __shared__ unsigned short Bs[4][128][8];
    __shared__ float csum[128], csq[128];
    const int tid = threadIdx.x;
    const int wave = tid >> 6, lane = tid & 63;
    const int chunkw = (blockIdx.x & 7) * (gridDim.x >> 3) + (blockIdx.x >> 3);
    const int r0 = chunkw * 128;
    const int n0 = 0;
    const int wr = wave >> 1, wc = wave & 1;
    const int kh = lane >> 4, l16 = lane & 15;

    if (tid < 128) { csum[tid] = 0.f; csq[tid] = 0.f; }

    f32x4 acc[4][4];
#pragma unroll
    for (int m = 0; m < 4; ++m)
#pragma unroll
        for (int n = 0; n < 4; ++n)
            acc[m][n] = (f32x4){0.f, 0.f, 0.f, 0.f};

    const int slotbase = wave * 64;
    int rowA[2];
#pragma unroll
    for (int pp = 0; pp < 2; ++pp)
        rowA[pp] = r0 + ((pp * 256 + slotbase + lane) & 127);

    for (int k0 = 0; k0 < C1_; k0 += 32) {
        __syncthreads();
#pragma unroll
        for (int pp = 0; pp < 2; ++pp) {
            const int sb = pp * 256 + slotbase;
            const int s = sb + lane;
            const int kg = s >> 7, i = s & 127;
            const unsigned short* gB = W + (size_t)(n0 + i) * C1_ + k0 + kg * 8;
            __builtin_amdgcn_global_load_lds(
                (const __attribute__((address_space(1))) void*)gB,
                (__attribute__((address_space(3))) void*)(&Bs[0][0][0] + (size_t)sb * 8),
                16, 0, 0);
            const int c0 = k0 + kg * 8;
            short8v v = *(const short8v*)(Abf + (size_t)rowA[pp] * C1_ + c0);
            float4 sca = *(const float4*)(scale + c0);
            float4 scb = *(const float4*)(scale + c0 + 4);
            float4 sha = *(const float4*)(shift + c0);
            float4 shb = *(const float4*)(shift + c0 + 4);
            float sc[8] = {sca.x, sca.y, sca.z, sca.w, scb.x, scb.y, scb.z, scb.w};
            float sh[8] = {sha.x, sha.y, sha.z, sha.w, shb.x, shb.y, shb.z, shb.w};
            short8v r;
#pragma unroll
            for (int j = 0; j < 8; ++j) {
                float f = bf2f((unsigned short)v[j]);
                f = fmaxf(fmaf(f, sc[j], sh[j]), 0.0f);
                r[j] = (short)f2bf(f);
            }
            *(short8v*)&As[kg][i][0] = r;
        }
        __syncthreads();

        short8v af[4], bf[4];
#pragma unroll
        for (int m = 0; m < 4; ++m)
            af[m] = *(const short8v*)&As[kh][wr * 64 + m * 16 + l16][0];
#pragma unroll
        for (int n = 0; n < 4; ++n)
            bf[n] = *(const short8v*)&Bs[kh][wc * 64 + n * 16 + l16][0];
#pragma unroll
        for (int m = 0; m < 4; ++m)
#pragma unroll
            for (int n = 0; n < 4; ++n)
                acc[m][n] = __builtin_amdgcn_mfma_f32_16x16x32_bf16(
                    af[m], bf[n], acc[m][n], 0, 0, 0);
    }

#pragma unroll
    for (int n = 0; n < 4; ++n) {
        const int cl = wc * 64 + n * 16 + l16;
        const int col = n0 + cl;
        const float bv = bias[col];
        float s = 0.f, qs = 0.f;
#pragma unroll
        for (int m = 0; m < 4; ++m) {
            const int rowb = r0 + wr * 64 + m * 16 + kh * 4;
#pragma unroll
            for (int j = 0; j < 4; ++j) {
                const float v = acc[m][n][j] + bv;
                s += v; qs += v * v;
                outf[(size_t)(rowb + j) * C2_ + col] = v;
            }
        }
        atomicAdd(&csum[cl], s);
        atomicAdd(&csq[cl], qs);
    }
    __syncthreads();
    if (tid < 128) {
        atomicAdd(&sums[n0 + tid], csum[tid]);
        atomicAdd(&ssqs[n0 + tid], csq[tid]);
    }
}

__global__ void finalize_kernel(const float* __restrict__ sums,
                                const float* __restrict__ ssqs,
                                const float* __restrict__ g,
                                const float* __restrict__ be,
                                float* __restrict__ scale,
                                float* __restrict__ shift, int C, float invCnt)
{
    int c = threadIdx.x;
    if (c < C) {
        float mu = sums[c] * invCnt;
        float var = ssqs[c] * invCnt - mu * mu;
        float sc = g[c] / sqrtf(var + 1e-5f);
        scale[c] = sc;
        shift[c] = be[c] - mu * sc;
    }
}

__global__ __launch_bounds__(256) void bnrelu_store_kernel(
    const float* __restrict__ y, const float* __restrict__ scale,
    const float* __restrict__ shift, float* __restrict__ out)
{
    int i = blockIdx.x * 256 + threadIdx.x;
    float4 v = ((const float4*)y)[i];
    int o = (i * 4) & (C2_ - 1);
    float4 sc = *(const float4*)(scale + o);
    float4 sh = *(const float4*)(shift + o);
    float4 r;
    r.x = fmaxf(fmaf(v.x, sc.x, sh.x), 0.0f);
    r.y = fmaxf(fmaf(v.y, sc.y, sh.y), 0.0f);
    r.z = fmaxf(fmaf(v.z, sc.z, sh.z), 0.0f);
    r.w = fmaxf(fmaf(v.w, sc.w, sh.w), 0.0f);
    ((float4*)out)[i] = r;
}

extern "C" void kernel_launch(void* const* d_in, const int* in_sizes, int n_in,
                              void* d_out, int out_size, void* d_ws, size_t ws_size,
                              hipStream_t stream)
{
    const float* xyz1    = (const float*)d_in[0];
    const float* xyz2    = (const float*)d_in[1];
    const float* points1 = (const float*)d_in[2];
    const float* points2 = (const float*)d_in[3];
    const float* w1  = (const float*)d_in[4];
    const float* b1  = (const float*)d_in[5];
    const float* g1  = (const float*)d_in[6];
    const float* be1 = (const float*)d_in[7];
    const float* w2  = (const float*)d_in[8];
    const float* b2  = (const float*)d_in[9];
    const float* g2  = (const float*)d_in[10];
    const float* be2 = (const float*)d_in[11];
    float* out = (float*)d_out;

    char* w = (char*)d_ws;
    float*          y2  = (float*)w;                             // 33,554,432
    unsigned short* y1b = (unsigned short*)(w + 50331648);       // 33,554,432
    char* tail = w + 83886080;
    int*   nidx = (int*)tail;                                    // 786,432
    float* nw   = (float*)(tail + 786432);                       // 786,432
    unsigned short* w1b = (unsigned short*)(tail + 1572864);     // 196,608
    unsigned short* w2b = (unsigned short*)(tail + 1769472);     // 65,536
    float* sum1   = (float*)(tail + 1835008);
    float* ssq1   = sum1 + 256;
    float* sum2   = ssq1 + 256;
    float* ssq2   = sum2 + 128;
    float* scale1 = ssq2 + 128;
    float* shift1 = scale1 + 256;
    float* scale2 = shift1 + 256;
    float* shift2 = scale2 + 128;
    float4* pk    = (float4*)(tail + 1843200);                   // 262,144

    hipMemsetAsync(sum1, 0, (256 + 256 + 128 + 128) * sizeof(float), stream);

    cvtw_kernel<<<dim3((C1_ * CIN_ + C2_ * C1_ + 255) / 256), 256, 0, stream>>>(w1, w2, w1b, w2b);
    pack_kernel<<<dim3(B_ * S_ / 256), 256, 0, stream>>>(xyz2, pk);

    nn3_kernel<<<dim3(N_ / 128, B_), 1024, 0, stream>>>(xyz1, pk, nidx, nw);

    gemm1_kernel<<<dim3(ROWS_ / 128 * 2), 256, 0, stream>>>(
        w1b, b1, points1, points2, nidx, nw, y1b, sum1, ssq1);
    finalize_kernel<<<1, 256, 0, stream>>>(sum1, ssq1, g1, be1, scale1, shift1, C1_, 1.0f / ROWS_);

    gemm2_kernel<<<dim3(ROWS_ / 128), 256, 0, stream>>>(
        y1b, w2b, b2, scale1, shift1, y2, sum2, ssq2);
    finalize_kernel<<<1, 256, 0, stream>>>(sum2, ssq2, g2, be2, scale2, shift2, C2_, 1.0f / ROWS_);

    bnrelu_store_kernel<<<dim3(ROWS_ * C2_ / 4 / 256), 256, 0, stream>>>(y2, scale2, shift2, out);
}

// Round 14
// 190.558 us; speedup vs baseline: 1.3923x; 1.0988x over previous
//
#include <hip/hip_runtime.h>
#include <hip/hip_bf16.h>

#define B_   8
#define N_   8192
#define S_   2048
#define D1_  128
#define D2_  256
#define CIN_ 384
#define C1_  256
#define C2_  128
#define ROWS_ (B_ * N_)   // 65536

typedef __attribute__((ext_vector_type(8))) short short8v;
typedef __attribute__((ext_vector_type(4))) float f32x4;
typedef __attribute__((ext_vector_type(16))) float f32x16;

__device__ inline unsigned short f2bf(float x) {
    __hip_bfloat16 h = __float2bfloat16(x);
    unsigned short u;
    __builtin_memcpy(&u, &h, 2);
    return u;
}
__device__ inline float bf2f(unsigned short u) {
    unsigned int x = ((unsigned int)u) << 16;
    float f;
    __builtin_memcpy(&f, &x, 4);
    return f;
}
__device__ inline unsigned int f2u(float x) { unsigned int u; __builtin_memcpy(&u, &x, 4); return u; }
__device__ inline float u2f(unsigned int u) { float x; __builtin_memcpy(&x, &u, 4); return x; }

// ---------------------------------------------------------------------------
// Pack xyz2 -> {x,y,z,r2} float4 (passed rounds 9-13; r2 bit-identical)
// ---------------------------------------------------------------------------
__global__ __launch_bounds__(256) void pack_kernel(
    const float* __restrict__ xyz2, float4* __restrict__ pk)
{
#pragma clang fp contract(off)
    int i = blockIdx.x * 256 + threadIdx.x;
    float a = xyz2[i * 3 + 0], c = xyz2[i * 3 + 1], d = xyz2[i * 3 + 2];
    float4 v; v.x = a; v.y = c; v.z = d; v.w = (a * a + c * c) + d * d;
    pk[i] = v;
}

// ---------------------------------------------------------------------------
// 3-NN single-pass (byte-identical to passing round 13)
// ---------------------------------------------------------------------------
__global__ __launch_bounds__(1024) void nn3_kernel(
    const float* __restrict__ xyz1, const float4* __restrict__ pk,
    int* __restrict__ nidx, float* __restrict__ nw)
{
#pragma clang fp contract(off)
    __shared__ unsigned int pv[8][128][3];
    __shared__ int          pi[8][128][3];
    const int tid = threadIdx.x;
    const int b = blockIdx.y;
    const int q = tid & 127;
    const int chunk = tid >> 7;
    const int s0 = chunk * 256;
    const unsigned s0u = __builtin_amdgcn_readfirstlane((unsigned)s0);
    const char* cp = (const char*)(pk + (size_t)b * S_) + (size_t)s0u * 16u;

    const int n = blockIdx.x * 128 + q;
    const float* p = xyz1 + ((size_t)b * N_ + n) * 3;
    const float px = p[0], py = p[1], pz = p[2];
    const float r1 = (px * px + py * py) + pz * pz;

    float e1 = 3.4e38f, e2 = 3.4e38f, e3 = 3.4e38f;
    int i1 = 0x7FFFFFFF, i2 = 0x7FFFFFFF, i3 = 0x7FFFFFFF;
    for (int g = 0; g < 16; ++g) {
        f32x16 c0, c1, c2, c3;
        asm volatile("s_load_dwordx16 %0, %4, 0\n\t"
                     "s_load_dwordx16 %1, %4, 64\n\t"
                     "s_load_dwordx16 %2, %4, 128\n\t"
                     "s_load_dwordx16 %3, %4, 192\n\t"
                     "s_waitcnt lgkmcnt(0)"
                     : "=&s"(c0), "=&s"(c1), "=&s"(c2), "=&s"(c3)
                     : "s"(cp + (size_t)g * 256));
#pragma unroll
        for (int j = 0; j < 16; ++j) {
            float sx = (j < 4) ? c0[4*j+0] : (j < 8) ? c1[4*(j-4)+0] : (j < 12) ? c2[4*(j-8)+0] : c3[4*(j-12)+0];
            float sy = (j < 4) ? c0[4*j+1] : (j < 8) ? c1[4*(j-4)+1] : (j < 12) ? c2[4*(j-8)+1] : c3[4*(j-12)+1];
            float sz = (j < 4) ? c0[4*j+2] : (j < 8) ? c1[4*(j-4)+2] : (j < 12) ? c2[4*(j-8)+2] : c3[4*(j-12)+2];
            float sr = (j < 4) ? c0[4*j+3] : (j < 8) ? c1[4*(j-4)+3] : (j < 12) ? c2[4*(j-8)+3] : c3[4*(j-12)+3];
            float dot = (px * sx + py * sy) + pz * sz;
            float d = (r1 - 2.0f * dot) + sr;
            const int s = s0 + g * 16 + j;
            bool lt1 = d < e1, lt2 = d < e2, lt3 = d < e3;
            float n1 = fminf(e1, d);
            float n2 = __builtin_amdgcn_fmed3f(d, e1, e2);
            float n3 = __builtin_amdgcn_fmed3f(d, e2, e3);
            int ni1 = lt1 ? s : i1;
            int ni2 = lt1 ? i1 : (lt2 ? s : i2);
            int ni3 = lt2 ? i2 : (lt3 ? s : i3);
            e1 = n1; e2 = n2; e3 = n3;
            i1 = ni1; i2 = ni2; i3 = ni3;
        }
    }
    pv[chunk][q][0] = f2u(e1); pv[chunk][q][1] = f2u(e2); pv[chunk][q][2] = f2u(e3);
    pi[chunk][q][0] = i1; pi[chunk][q][1] = i2; pi[chunk][q][2] = i3;
    __syncthreads();

    if (tid < 128) {
        float m1 = u2f(pv[0][tid][0]), m2 = u2f(pv[0][tid][1]), m3 = u2f(pv[0][tid][2]);
        int j1 = pi[0][tid][0], j2 = pi[0][tid][1], j3 = pi[0][tid][2];
#pragma unroll
        for (int c = 1; c < 8; ++c) {
#pragma unroll
            for (int e = 0; e < 3; ++e) {
                float x = u2f(pv[c][tid][e]);
                int   xi = pi[c][tid][e];
                bool lt1 = x < m1, lt2 = x < m2, lt3 = x < m3;
                float n1 = fminf(m1, x);
                float n2 = __builtin_amdgcn_fmed3f(x, m1, m2);
                float n3 = __builtin_amdgcn_fmed3f(x, m2, m3);
                int nj1 = lt1 ? xi : j1;
                int nj2 = lt1 ? j1 : (lt2 ? xi : j2);
                int nj3 = lt2 ? j2 : (lt3 ? xi : j3);
                m1 = n1; m2 = n2; m3 = n3;
                j1 = nj1; j2 = nj2; j3 = nj3;
            }
        }
        float ra = 1.0f / (m1 + 1e-8f);
        float rb = 1.0f / (m2 + 1e-8f);
        float rc = 1.0f / (m3 + 1e-8f);
        float sum = (ra + rb) + rc;
        size_t o = ((size_t)b * N_ + blockIdx.x * 128 + tid) * 3;
        nidx[o + 0] = j1; nidx[o + 1] = j2; nidx[o + 2] = j3;
        nw[o + 0] = ra / sum; nw[o + 1] = rb / sum; nw[o + 2] = rc / sum;
    }
}

// weights -> bf16
__global__ void cvtw_kernel(const float* __restrict__ w1, const float* __restrict__ w2,
                            unsigned short* __restrict__ w1b, unsigned short* __restrict__ w2b)
{
    int i = blockIdx.x * 256 + threadIdx.x;
    if (i < C1_ * CIN_) w1b[i] = f2bf(w1[i]);
    else {
        int j = i - C1_ * CIN_;
        if (j < C2_ * C1_) w2b[j] = f2bf(w2[j]);
    }
}

// ---------------------------------------------------------------------------
// GEMM1 FAT-STEP: BM=256 x BN=256 x BK=64, 8 waves (512 thr), 6 K-steps.
// 64 MFMA per wave per barrier-drain (4x round-13) -> latency amortized.
// A built in-flight (concat p1 | interp p2), arithmetic bit-identical to
// the passing MODE2. Fused bias + BN-stats. Output bf16.
// Wave (wr=wave>>2, wc=wave&3) owns 128x64 out; frags acc[8][4].
// Staging bijection: slot s = t*512+tid -> kg=s>>8, row=s&255; per thread
// row=tid&255 fixed, kg = 2t + (tid>>8).
// ---------------------------------------------------------------------------
__global__ __launch_bounds__(512) void gemm1_kernel(
    const unsigned short* __restrict__ W,    // w1b [256][384]
    const float* __restrict__ bias,
    const float* __restrict__ p1,
    const float* __restrict__ p2,
    const int* __restrict__ nidx,
    const float* __restrict__ nw,
    unsigned short* __restrict__ out,        // y1b [65536][256]
    float* __restrict__ sums, float* __restrict__ ssqs)
{
    __shared__ unsigned short As[8][256][8];   // 32 KiB
    __shared__ unsigned short Bs[8][256][8];   // 32 KiB
    __shared__ float csum[256], csq[256];
    __shared__ int   lidx[256][3];
    __shared__ float lw[256][3];
    const int tid = threadIdx.x;               // 0..511
    const int wave = tid >> 6, lane = tid & 63;
    const int chunkw = (blockIdx.x & 7) * (gridDim.x >> 3) + (blockIdx.x >> 3);
    const int r0 = chunkw * 256;
    const int wr = wave >> 2, wc = wave & 3;
    const int kh = lane >> 4, l16 = lane & 15;
    const int irow = tid & 255;                // row this thread stages
    const int hi = tid >> 8;                   // 0/1

    if (tid < 256) {
        csum[tid] = 0.f; csq[tid] = 0.f;
        const int row = r0 + tid;
        lidx[tid][0] = nidx[row * 3 + 0];
        lidx[tid][1] = nidx[row * 3 + 1];
        lidx[tid][2] = nidx[row * 3 + 2];
        lw[tid][0] = nw[row * 3 + 0];
        lw[tid][1] = nw[row * 3 + 1];
        lw[tid][2] = nw[row * 3 + 2];
    }
    __syncthreads();
    const int gj0 = lidx[irow][0], gj1 = lidx[irow][1], gj2 = lidx[irow][2];
    const float gw0 = lw[irow][0], gw1 = lw[irow][1], gw2 = lw[irow][2];
    const float* p2b = p2 + (size_t)(r0 >> 13) * S_ * D2_;   // block-uniform batch

    f32x4 acc[8][4];
#pragma unroll
    for (int m = 0; m < 8; ++m)
#pragma unroll
        for (int n = 0; n < 4; ++n)
            acc[m][n] = (f32x4){0.f, 0.f, 0.f, 0.f};

    for (int k0 = 0; k0 < CIN_; k0 += 64) {
        __syncthreads();   // previous step's LDS reads complete
        // stage B: 2048 slots, global_load_lds 16B each (4/thread)
#pragma unroll
        for (int t = 0; t < 4; ++t) {
            const int sb = t * 512 + wave * 64;          // wave-uniform
            const int s = sb + lane;
            const int bkg = s >> 8, bi = s & 255;
            const unsigned short* gB = W + (size_t)bi * CIN_ + k0 + bkg * 8;
            __builtin_amdgcn_global_load_lds(
                (const __attribute__((address_space(1))) void*)gB,
                (__attribute__((address_space(3))) void*)(&Bs[0][0][0] + (size_t)sb * 8),
                16, 0, 0);
        }
        // stage A: per thread 4 octets of its row (kg = 2t+hi)
#pragma unroll
        for (int t = 0; t < 4; ++t) {
            const int kg = t * 2 + hi;
            const int cc0 = k0 + kg * 8;
            short8v r;
            if (k0 < D1_) {          // whole step reads points1 (cc0 < 128)
                const float* qq = p1 + (size_t)(r0 + irow) * D1_ + cc0;
                float4 a = *(const float4*)qq;
                float4 bq = *(const float4*)(qq + 4);
                float tt[8] = {a.x, a.y, a.z, a.w, bq.x, bq.y, bq.z, bq.w};
#pragma unroll
                for (int j = 0; j < 8; ++j) r[j] = (short)f2bf(tt[j]);
            } else {                 // interp region
                const int cc = cc0 - D1_;
                const float* q0 = p2b + (size_t)gj0 * D2_ + cc;
                const float* q1 = p2b + (size_t)gj1 * D2_ + cc;
                const float* q2 = p2b + (size_t)gj2 * D2_ + cc;
                float4 x0 = *(const float4*)q0, x0b = *(const float4*)(q0 + 4);
                float4 x1 = *(const float4*)q1, x1b = *(const float4*)(q1 + 4);
                float4 x2 = *(const float4*)q2, x2b = *(const float4*)(q2 + 4);
                float a0[8] = {x0.x, x0.y, x0.z, x0.w, x0b.x, x0b.y, x0b.z, x0b.w};
                float a1[8] = {x1.x, x1.y, x1.z, x1.w, x1b.x, x1b.y, x1b.z, x1b.w};
                float a2[8] = {x2.x, x2.y, x2.z, x2.w, x2b.x, x2b.y, x2b.z, x2b.w};
#pragma unroll
                for (int j = 0; j < 8; ++j)
                    r[j] = (short)f2bf(a0[j] * gw0 + a1[j] * gw1 + a2[j] * gw2);
            }
            *(short8v*)&As[kg][irow][0] = r;
        }
        __syncthreads();

        // MFMA: 2 K=32 chunks, 8x4 frags -> 64 MFMA/wave/step
#pragma unroll
        for (int kk = 0; kk < 2; ++kk) {
            short8v af[8], bf[4];
#pragma unroll
            for (int m = 0; m < 8; ++m)
                af[m] = *(const short8v*)&As[kk * 4 + kh][wr * 128 + m * 16 + l16][0];
#pragma unroll
            for (int n = 0; n < 4; ++n)
                bf[n] = *(const short8v*)&Bs[kk * 4 + kh][wc * 64 + n * 16 + l16][0];
#pragma unroll
            for (int m = 0; m < 8; ++m)
#pragma unroll
                for (int n = 0; n < 4; ++n)
                    acc[m][n] = __builtin_amdgcn_mfma_f32_16x16x32_bf16(
                        af[m], bf[n], acc[m][n], 0, 0, 0);
        }
    }

    // epilogue: +bias, store, per-channel stats
#pragma unroll
    for (int n = 0; n < 4; ++n) {
        const int col = wc * 64 + n * 16 + l16;   // 0..255
        const float bv = bias[col];
        float s = 0.f, qs = 0.f;
#pragma unroll
        for (int m = 0; m < 8; ++m) {
            const int rl = wr * 128 + m * 16 + kh * 4;
#pragma unroll
            for (int j = 0; j < 4; ++j) {
                const float v = acc[m][n][j] + bv;
                s += v; qs += v * v;
                out[(size_t)(r0 + rl + j) * C1_ + col] = f2bf(v);
            }
        }
        atomicAdd(&csum[col], s);
        atomicAdd(&csq[col], qs);
    }
    __syncthreads();
    if (tid < 256) {
        atomicAdd(&sums[tid], csum[tid]);
        atomicAdd(&ssqs[tid], csq[tid]);
    }
}

// ---------------------------------------------------------------------------
// GEMM2 (byte-identical to passing rounds 10-13): A = relu(y1b*scale+shift)
// reg-staged; fused bias + stats. Output f32.
// ---------------------------------------------------------------------------
__global__ __launch_bounds__(256) void gemm2_kernel(
    const unsigned short* __restrict__ Abf,
    const unsigned short* __restrict__ W,
    const float* __restrict__ bias,
    const float* __restrict__ scale, const float* __restrict__ shift,
    float* __restrict__ outf,
    float* __restrict__ sums, float* __restrict__ ssqs)
{
    __shared__ unsigned short As[4][128][8];
    __shared__ unsigned short Bs[4][128][8];
    __shared__ float csum[128], csq[128];
    const int tid = threadIdx.x;
    const int wave = tid >> 6, lane = tid & 63;
    const int chunkw = (blockIdx.x & 7) * (gridDim.x >> 3) + (blockIdx.x >> 3);
    const int r0 = chunkw * 128;
    const int n0 = 0;
    const int wr = wave >> 1, wc = wave & 1;
    const int kh = lane >> 4, l16 = lane & 15;

    if (tid < 128) { csum[tid] = 0.f; csq[tid] = 0.f; }

    f32x4 acc[4][4];
#pragma unroll
    for (int m = 0; m < 4; ++m)
#pragma unroll
        for (int n = 0; n < 4; ++n)
            acc[m][n] = (f32x4){0.f, 0.f, 0.f, 0.f};

    const int slotbase = wave * 64;
    int rowA[2];
#pragma unroll
    for (int pp = 0; pp < 2; ++pp)
        rowA[pp] = r0 + ((pp * 256 + slotbase + lane) & 127);

    for (int k0 = 0; k0 < C1_; k0 += 32) {
        __syncthreads();
#pragma unroll
        for (int pp = 0; pp < 2; ++pp) {
            const int sb = pp * 256 + slotbase;
            const int s = sb + lane;
            const int kg = s >> 7, i = s & 127;
            const unsigned short* gB = W + (size_t)(n0 + i) * C1_ + k0 + kg * 8;
            __builtin_amdgcn_global_load_lds(
                (const __attribute__((address_space(1))) void*)gB,
                (__attribute__((address_space(3))) void*)(&Bs[0][0][0] + (size_t)sb * 8),
                16, 0, 0);
            const int c0 = k0 + kg * 8;
            short8v v = *(const short8v*)(Abf + (size_t)rowA[pp] * C1_ + c0);
            float4 sca = *(const float4*)(scale + c0);
            float4 scb = *(const float4*)(scale + c0 + 4);
            float4 sha = *(const float4*)(shift + c0);
            float4 shb = *(const float4*)(shift + c0 + 4);
            float sc[8] = {sca.x, sca.y, sca.z, sca.w, scb.x, scb.y, scb.z, scb.w};
            float sh[8] = {sha.x, sha.y, sha.z, sha.w, shb.x, shb.y, shb.z, shb.w};
            short8v r;
#pragma unroll
            for (int j = 0; j < 8; ++j) {
                float f = bf2f((unsigned short)v[j]);
                f = fmaxf(fmaf(f, sc[j], sh[j]), 0.0f);
                r[j] = (short)f2bf(f);
            }
            *(short8v*)&As[kg][i][0] = r;
        }
        __syncthreads();

        short8v af[4], bf[4];
#pragma unroll
        for (int m = 0; m < 4; ++m)
            af[m] = *(const short8v*)&As[kh][wr * 64 + m * 16 + l16][0];
#pragma unroll
        for (int n = 0; n < 4; ++n)
            bf[n] = *(const short8v*)&Bs[kh][wc * 64 + n * 16 + l16][0];
#pragma unroll
        for (int m = 0; m < 4; ++m)
#pragma unroll
            for (int n = 0; n < 4; ++n)
                acc[m][n] = __builtin_amdgcn_mfma_f32_16x16x32_bf16(
                    af[m], bf[n], acc[m][n], 0, 0, 0);
    }

#pragma unroll
    for (int n = 0; n < 4; ++n) {
        const int cl = wc * 64 + n * 16 + l16;
        const int col = n0 + cl;
        const float bv = bias[col];
        float s = 0.f, qs = 0.f;
#pragma unroll
        for (int m = 0; m < 4; ++m) {
            const int rowb = r0 + wr * 64 + m * 16 + kh * 4;
#pragma unroll
            for (int j = 0; j < 4; ++j) {
                const float v = acc[m][n][j] + bv;
                s += v; qs += v * v;
                outf[(size_t)(rowb + j) * C2_ + col] = v;
            }
        }
        atomicAdd(&csum[cl], s);
        atomicAdd(&csq[cl], qs);
    }
    __syncthreads();
    if (tid < 128) {
        atomicAdd(&sums[n0 + tid], csum[tid]);
        atomicAdd(&ssqs[n0 + tid], csq[tid]);
    }
}

__global__ void finalize_kernel(const float* __restrict__ sums,
                                const float* __restrict__ ssqs,
                                const float* __restrict__ g,
                                const float* __restrict__ be,
                                float* __restrict__ scale,
                                float* __restrict__ shift, int C, float invCnt)
{
    int c = threadIdx.x;
    if (c < C) {
        float mu = sums[c] * invCnt;
        float var = ssqs[c] * invCnt - mu * mu;
        float sc = g[c] / sqrtf(var + 1e-5f);
        scale[c] = sc;
        shift[c] = be[c] - mu * sc;
    }
}

__global__ __launch_bounds__(256) void bnrelu_store_kernel(
    const float* __restrict__ y, const float* __restrict__ scale,
    const float* __restrict__ shift, float* __restrict__ out)
{
    int i = blockIdx.x * 256 + threadIdx.x;
    float4 v = ((const float4*)y)[i];
    int o = (i * 4) & (C2_ - 1);
    float4 sc = *(const float4*)(scale + o);
    float4 sh = *(const float4*)(shift + o);
    float4 r;
    r.x = fmaxf(fmaf(v.x, sc.x, sh.x), 0.0f);
    r.y = fmaxf(fmaf(v.y, sc.y, sh.y), 0.0f);
    r.z = fmaxf(fmaf(v.z, sc.z, sh.z), 0.0f);
    r.w = fmaxf(fmaf(v.w, sc.w, sh.w), 0.0f);
    ((float4*)out)[i] = r;
}

extern "C" void kernel_launch(void* const* d_in, const int* in_sizes, int n_in,
                              void* d_out, int out_size, void* d_ws, size_t ws_size,
                              hipStream_t stream)
{
    const float* xyz1    = (const float*)d_in[0];
    const float* xyz2    = (const float*)d_in[1];
    const float* points1 = (const float*)d_in[2];
    const float* points2 = (const float*)d_in[3];
    const float* w1  = (const float*)d_in[4];
    const float* b1  = (const float*)d_in[5];
    const float* g1  = (const float*)d_in[6];
    const float* be1 = (const float*)d_in[7];
    const float* w2  = (const float*)d_in[8];
    const float* b2  = (const float*)d_in[9];
    const float* g2  = (const float*)d_in[10];
    const float* be2 = (const float*)d_in[11];
    float* out = (float*)d_out;

    char* w = (char*)d_ws;
    float*          y2  = (float*)w;                             // 33,554,432
    unsigned short* y1b = (unsigned short*)(w + 50331648);       // 33,554,432
    char* tail = w + 83886080;
    int*   nidx = (int*)tail;                                    // 786,432
    float* nw   = (float*)(tail + 786432);                       // 786,432
    unsigned short* w1b = (unsigned short*)(tail + 1572864);     // 196,608
    unsigned short* w2b = (unsigned short*)(tail + 1769472);     // 65,536
    float* sum1   = (float*)(tail + 1835008);
    float* ssq1   = sum1 + 256;
    float* sum2   = ssq1 + 256;
    float* ssq2   = sum2 + 128;
    float* scale1 = ssq2 + 128;
    float* shift1 = scale1 + 256;
    float* scale2 = shift1 + 256;
    float* shift2 = scale2 + 128;
    float4* pk    = (float4*)(tail + 1843200);                   // 262,144

    hipMemsetAsync(sum1, 0, (256 + 256 + 128 + 128) * sizeof(float), stream);

    cvtw_kernel<<<dim3((C1_ * CIN_ + C2_ * C1_ + 255) / 256), 256, 0, stream>>>(w1, w2, w1b, w2b);
    pack_kernel<<<dim3(B_ * S_ / 256), 256, 0, stream>>>(xyz2, pk);

    nn3_kernel<<<dim3(N_ / 128, B_), 1024, 0, stream>>>(xyz1, pk, nidx, nw);

    gemm1_kernel<<<dim3(ROWS_ / 256), 512, 0, stream>>>(
        w1b, b1, points1, points2, nidx, nw, y1b, sum1, ssq1);
    finalize_kernel<<<1, 256, 0, stream>>>(sum1, ssq1, g1, be1, scale1, shift1, C1_, 1.0f / ROWS_);

    gemm2_kernel<<<dim3(ROWS_ / 128), 256, 0, stream>>>(
        y1b, w2b, b2, scale1, shift1, y2, sum2, ssq2);
    finalize_kernel<<<1, 256, 0, stream>>>(sum2, ssq2, g2, be2, scale2, shift2, C2_, 1.0f / ROWS_);

    bnrelu_store_kernel<<<dim3(ROWS_ * C2_ / 4 / 256), 256, 0, stream>>>(y2, scale2, shift2, out);
}